// Round 1
// baseline (494.090 us; speedup 1.0000x reference)
//
#include <hip/hip_runtime.h>
#include <stdint.h>

// Problem constants
#define BB 2
#define SS 2048
#define DD 1024
#define HH 16
#define DH 64
#define MM 4096   // BB*SS

typedef __attribute__((ext_vector_type(8))) short short8;
typedef __attribute__((ext_vector_type(4))) float floatx4;
typedef unsigned short u16;

#define MFMA16(a,b,c) __builtin_amdgcn_mfma_f32_16x16x32_bf16((a),(b),(c),0,0,0)

__device__ __forceinline__ u16 f2bf(float f) {
  unsigned u = __float_as_uint(f);
  u += 0x7fffu + ((u >> 16) & 1u);
  return (u16)(u >> 16);
}

__device__ __forceinline__ void gll16(const void* g, void* l) {
  __builtin_amdgcn_global_load_lds((const __attribute__((address_space(1))) void*)g,
                                   (__attribute__((address_space(3))) void*)l,
                                   16, 0, 0);
}

// ---------------- sin/cos table: tab[s*32+j] = (sin(s*inv_j), cos(s*inv_j))
__global__ __launch_bounds__(256) void sincos_k(float2* __restrict__ tab) {
  const int t = blockIdx.x * 256 + threadIdx.x;   // S*32 threads
  const int s = t >> 5, j = t & 31;
  const float inv = expf(-(float)j * (0.125f * 2.302585092994046f)); // 10^(-j/8)
  const float a = (float)s * inv;
  tab[t] = make_float2(sinf(a), cosf(a));
}

// ---------------- fp32 -> bf16 converters
__global__ __launch_bounds__(256) void conv_qkv(const float* __restrict__ a, const float* __restrict__ b,
                                                const float* __restrict__ c,
                                                u16* __restrict__ oa, u16* __restrict__ ob, u16* __restrict__ oc) {
  const float* s = blockIdx.y == 0 ? a : (blockIdx.y == 1 ? b : c);
  u16* d = blockIdx.y == 0 ? oa : (blockIdx.y == 1 ? ob : oc);
  const int i = (blockIdx.x * 256 + threadIdx.x) * 4;
  const float4 x = *(const float4*)(s + i);
  ushort4 p; p.x = f2bf(x.x); p.y = f2bf(x.y); p.z = f2bf(x.z); p.w = f2bf(x.w);
  *(ushort4*)(d + i) = p;
}

__global__ __launch_bounds__(256) void conv_w(const float* __restrict__ a, const float* __restrict__ b,
                                              const float* __restrict__ c, const float* __restrict__ d4,
                                              u16* __restrict__ oa, u16* __restrict__ ob,
                                              u16* __restrict__ oc, u16* __restrict__ od) {
  const float* s = blockIdx.y == 0 ? a : (blockIdx.y == 1 ? b : (blockIdx.y == 2 ? c : d4));
  u16* d = blockIdx.y == 0 ? oa : (blockIdx.y == 1 ? ob : (blockIdx.y == 2 ? oc : od));
  const int i = (blockIdx.x * 256 + threadIdx.x) * 4;
  const float4 x = *(const float4*)(s + i);
  ushort4 p; p.x = f2bf(x.x); p.y = f2bf(x.y); p.z = f2bf(x.z); p.w = f2bf(x.w);
  *(ushort4*)(d + i) = p;
}

// ---------------- GEMM: C[M][N] = A[M][K](bf16) * Bt[N][K](bf16)^T + bias[N], fp32 out
// 128x128 tile, BK=32, 256 threads (4 waves, 2x2), m97 structure.
__global__ __launch_bounds__(256) void gemm_bt(const u16* __restrict__ A, const u16* __restrict__ Bt,
                                               const float* __restrict__ bias, float* __restrict__ C,
                                               int M, int N, int K) {
  __shared__ alignas(16) u16 As[128 * 32];
  __shared__ alignas(16) u16 Bs[128 * 32];
  const int tid = threadIdx.x;
  const int w = tid >> 6, l = tid & 63;
  const int lr = l & 15, lq = l >> 4;
  const int m0 = blockIdx.y * 128, n0 = blockIdx.x * 128;
  const int wm = (w >> 1) * 64, wn = (w & 1) * 64;

  floatx4 acc[4][4];
#pragma unroll
  for (int i = 0; i < 4; ++i)
#pragma unroll
    for (int j = 0; j < 4; ++j) acc[i][j] = (floatx4){0.f, 0.f, 0.f, 0.f};

  // staging: wave w owns rows [32w, 32w+32) of each tile; lane covers row +l/4, col8 = (l&3)*8
  const int srow = w * 32 + (l >> 2);
  const int scol = (l & 3) * 8;
  const u16* ag = A + (size_t)(m0 + srow) * K + scol;
  const u16* bg = Bt + (size_t)(n0 + srow) * K + scol;
  u16* as0 = &As[w * 1024];
  u16* bs0 = &Bs[w * 1024];

  for (int k0 = 0; k0 < K; k0 += 32) {
    gll16(ag + k0, as0);
    gll16(ag + (size_t)16 * K + k0, as0 + 512);
    gll16(bg + k0, bs0);
    gll16(bg + (size_t)16 * K + k0, bs0 + 512);
    __syncthreads();
    short8 af[4], bfv[4];
#pragma unroll
    for (int i = 0; i < 4; ++i) af[i] = *(const short8*)&As[(wm + i * 16 + lr) * 32 + lq * 8];
#pragma unroll
    for (int j = 0; j < 4; ++j) bfv[j] = *(const short8*)&Bs[(wn + j * 16 + lr) * 32 + lq * 8];
#pragma unroll
    for (int i = 0; i < 4; ++i)
#pragma unroll
      for (int j = 0; j < 4; ++j) acc[i][j] = MFMA16(af[i], bfv[j], acc[i][j]);
    __syncthreads();
  }

#pragma unroll
  for (int i = 0; i < 4; ++i) {
    const int row = m0 + wm + i * 16 + lq * 4;
#pragma unroll
    for (int j = 0; j < 4; ++j) {
      const int col = n0 + wn + j * 16 + lr;
      const float bv = bias[col];
      float* cp = C + (size_t)row * N + col;
#pragma unroll
      for (int r = 0; r < 4; ++r) cp[(size_t)r * N] = acc[i][j][r] + bv;
    }
  }
}

// ---------------- RoPE + repack: Qlin/Klin fp32 [b*S+s][h*64+e] -> bf16 [b][h][s][64]
__global__ __launch_bounds__(256) void rope_post(const float* __restrict__ Qlin, const float* __restrict__ Klin,
                                                 const float2* __restrict__ tab,
                                                 u16* __restrict__ Qo, u16* __restrict__ Ko) {
  const int t = blockIdx.x * 256 + threadIdx.x;   // MM*DD/2 threads
  const int j = t & 31;
  const int h = (t >> 5) & 15;
  const int row = t >> 9;            // b*S + s
  const int s = row & (SS - 1);
  const int b = row >> 11;
  const float* src = blockIdx.z ? Klin : Qlin;
  u16* dst = blockIdx.z ? Ko : Qo;
  const float2 x = *(const float2*)(src + (size_t)row * DD + h * 64 + 2 * j);
  const float2 sc = tab[s * 32 + j];
  const float e = x.x * sc.x - x.y * sc.y;    //  x1*sin - x2*cos
  const float o = -x.x * sc.y - x.y * sc.x;   // -x1*cos - x2*sin
  const size_t oi = ((size_t)(b * HH + h) * SS + s) * DH + 2 * j;
  ushort2 pk; pk.x = f2bf(e); pk.y = f2bf(o);
  *(ushort2*)(dst + oi) = pk;
}

// ---------------- V: bias already added; fp32 [b*S+s][h*64+e] -> bf16 transposed [bh][e][s]
__global__ __launch_bounds__(256) void v_post(const float* __restrict__ Vlin, u16* __restrict__ Vt) {
  __shared__ alignas(16) u16 tile[64][72];
  const int s0 = blockIdx.x * 64;
  const int bh = blockIdx.y;
  const int b = bh >> 4, h = bh & 15;
  const int t = threadIdx.x;
  const int sr = t >> 4;
  const int e4 = (t & 15) * 4;
#pragma unroll
  for (int it = 0; it < 4; ++it) {
    const int srow = sr + it * 16;
    const float4 x = *(const float4*)(Vlin + ((size_t)(b * SS + s0 + srow)) * DD + h * 64 + e4);
    tile[e4 + 0][srow] = f2bf(x.x);
    tile[e4 + 1][srow] = f2bf(x.y);
    tile[e4 + 2][srow] = f2bf(x.z);
    tile[e4 + 3][srow] = f2bf(x.w);
  }
  __syncthreads();
  const int e = t >> 2;
  const int sc = (t & 3) * 16;
  u16* op = Vt + ((size_t)bh * DH + e) * SS + s0 + sc;
  *(short8*)op = *(const short8*)&tile[e][sc];
  *(short8*)(op + 8) = *(const short8*)&tile[e][sc + 8];
}

// ---------------- causal flash attention: Q,K bf16 [bh][s][64], V bf16 [bh][64][s] -> O bf16 [b][s][h*64+e]
__global__ __launch_bounds__(256) void attn_fwd(const u16* __restrict__ Qr, const u16* __restrict__ Kr,
                                                const u16* __restrict__ Vt, u16* __restrict__ O) {
  __shared__ alignas(16) u16 P[4][16][72];
  const int bh = blockIdx.y;
  const int w = threadIdx.x >> 6, l = threadIdx.x & 63;
  const int lr = l & 15, lq = l >> 4;
  const int q0 = blockIdx.x * 64 + w * 16;     // this wave's 16 q rows
  const u16* Qh = Qr + (size_t)bh * SS * DH;
  const u16* Kh = Kr + (size_t)bh * SS * DH;
  const u16* Vh = Vt + (size_t)bh * DH * SS;

  const short8 qf0 = *(const short8*)(Qh + (size_t)(q0 + lr) * DH + lq * 8);
  const short8 qf1 = *(const short8*)(Qh + (size_t)(q0 + lr) * DH + 32 + lq * 8);

  floatx4 oacc[4];
#pragma unroll
  for (int n = 0; n < 4; ++n) oacc[n] = (floatx4){0.f, 0.f, 0.f, 0.f};
  float mrun[4] = {-1e30f, -1e30f, -1e30f, -1e30f};
  float lrun[4] = {0.f, 0.f, 0.f, 0.f};

  const int kvend = q0 + 16;
  for (int kv0 = 0; kv0 < kvend; kv0 += 64) {
    floatx4 s[4];
#pragma unroll
    for (int t = 0; t < 4; ++t) {
      const u16* kp = Kh + (size_t)(kv0 + t * 16 + lr) * DH + lq * 8;
      floatx4 z = (floatx4){0.f, 0.f, 0.f, 0.f};
      z = MFMA16(qf0, *(const short8*)kp, z);
      z = MFMA16(qf1, *(const short8*)(kp + 32), z);
      s[t] = z;
    }
    if (kv0 + 63 > q0) {   // diagonal tiles: mask k > q
#pragma unroll
      for (int t = 0; t < 4; ++t) {
        const int kcol = kv0 + t * 16 + lr;
#pragma unroll
        for (int r = 0; r < 4; ++r)
          if (kcol > q0 + lq * 4 + r) s[t][r] = -1e30f;
      }
    }
    float scale[4];
#pragma unroll
    for (int r = 0; r < 4; ++r) {
      float mx = fmaxf(fmaxf(s[0][r], s[1][r]), fmaxf(s[2][r], s[3][r]));
      mx = fmaxf(mx, __shfl_xor(mx, 1));
      mx = fmaxf(mx, __shfl_xor(mx, 2));
      mx = fmaxf(mx, __shfl_xor(mx, 4));
      mx = fmaxf(mx, __shfl_xor(mx, 8));
      const float mn = fmaxf(mrun[r], mx);
      scale[r] = __expf(mrun[r] - mn);
      mrun[r] = mn;
      float rs = 0.f;
#pragma unroll
      for (int t = 0; t < 4; ++t) {
        const float p = __expf(s[t][r] - mn);
        s[t][r] = p;
        rs += p;
      }
      rs += __shfl_xor(rs, 1);
      rs += __shfl_xor(rs, 2);
      rs += __shfl_xor(rs, 4);
      rs += __shfl_xor(rs, 8);
      lrun[r] = lrun[r] * scale[r] + rs;
    }
    const floatx4 sv = {scale[0], scale[1], scale[2], scale[3]};
#pragma unroll
    for (int n = 0; n < 4; ++n) oacc[n] *= sv;
#pragma unroll
    for (int t = 0; t < 4; ++t)
#pragma unroll
      for (int r = 0; r < 4; ++r)
        P[w][lq * 4 + r][t * 16 + lr] = f2bf(s[t][r]);
    // same-wave LDS RAW: compiler inserts lgkmcnt waits
#pragma unroll
    for (int kk = 0; kk < 2; ++kk) {
      const short8 pf = *(const short8*)&P[w][lr][kk * 32 + lq * 8];
#pragma unroll
      for (int n = 0; n < 4; ++n) {
        const u16* vp = Vh + (size_t)(n * 16 + lr) * SS + kv0 + kk * 32 + lq * 8;
        oacc[n] = MFMA16(pf, *(const short8*)vp, oacc[n]);
      }
    }
  }
  const int b = bh >> 4, h = bh & 15;
#pragma unroll
  for (int n = 0; n < 4; ++n)
#pragma unroll
    for (int r = 0; r < 4; ++r) {
      const int qrow = q0 + lq * 4 + r;
      const float ov = oacc[n][r] / lrun[r];
      O[((size_t)(b * SS + qrow)) * DD + h * DH + n * 16 + lr] = f2bf(ov);
    }
}

extern "C" void kernel_launch(void* const* d_in, const int* in_sizes, int n_in,
                              void* d_out, int out_size, void* d_ws, size_t ws_size,
                              hipStream_t stream) {
  (void)in_sizes; (void)n_in; (void)out_size; (void)ws_size;
  const float* q  = (const float*)d_in[0];
  const float* k  = (const float*)d_in[1];
  const float* v  = (const float*)d_in[2];
  const float* Wq = (const float*)d_in[3];
  const float* bq = (const float*)d_in[4];
  const float* Wk = (const float*)d_in[5];
  const float* bk = (const float*)d_in[6];
  const float* Wv = (const float*)d_in[7];
  const float* bv = (const float*)d_in[8];
  const float* Wo = (const float*)d_in[9];
  const float* bo = (const float*)d_in[10];
  float* out = (float*)d_out;

  char* ws = (char*)d_ws;
  size_t off = 0;
  auto carve = [&](size_t bytes) { char* p = ws + off; off += (bytes + 255) & ~(size_t)255; return p; };
  u16* qb   = (u16*)carve((size_t)MM * DD * 2);
  u16* kb   = (u16*)carve((size_t)MM * DD * 2);
  u16* vb   = (u16*)carve((size_t)MM * DD * 2);
  u16* wqb  = (u16*)carve((size_t)DD * DD * 2);
  u16* wkb  = (u16*)carve((size_t)DD * DD * 2);
  u16* wvb  = (u16*)carve((size_t)DD * DD * 2);
  u16* wob  = (u16*)carve((size_t)DD * DD * 2);
  float* Qlin = (float*)carve((size_t)MM * DD * 4);
  float* Klin = (float*)carve((size_t)MM * DD * 4);
  float* Vlin = (float*)carve((size_t)MM * DD * 4);
  u16* Vtr  = (u16*)carve((size_t)MM * DD * 2);
  float2* tab = (float2*)carve((size_t)SS * 32 * 8);
  // reuse: after the three projection GEMMs, qb/kb/vb are dead
  u16* Qro = qb;
  u16* Kro = kb;
  u16* Ob  = vb;

  sincos_k<<<SS * 32 / 256, 256, 0, stream>>>(tab);
  conv_qkv<<<dim3(MM * DD / 1024, 3), 256, 0, stream>>>(q, k, v, qb, kb, vb);
  conv_w<<<dim3(DD * DD / 1024, 4), 256, 0, stream>>>(Wq, Wk, Wv, Wo, wqb, wkb, wvb, wob);
  gemm_bt<<<dim3(DD / 128, MM / 128), 256, 0, stream>>>(qb, wqb, bq, Qlin, MM, DD, DD);
  gemm_bt<<<dim3(DD / 128, MM / 128), 256, 0, stream>>>(kb, wkb, bk, Klin, MM, DD, DD);
  gemm_bt<<<dim3(DD / 128, MM / 128), 256, 0, stream>>>(vb, wvb, bv, Vlin, MM, DD, DD);
  rope_post<<<dim3(MM * DD / 2 / 256, 1, 2), 256, 0, stream>>>(Qlin, Klin, tab, Qro, Kro);
  v_post<<<dim3(SS / 64, BB * HH), 256, 0, stream>>>(Vlin, Vtr);
  attn_fwd<<<dim3(SS / 64, BB * HH), 256, 0, stream>>>(Qro, Kro, Vtr, Ob);
  gemm_bt<<<dim3(DD / 128, MM / 128), 256, 0, stream>>>(Ob, wob, bo, out, MM, DD, DD);
}

// Round 2
// 287.887 us; speedup vs baseline: 1.7163x; 1.7163x over previous
//
#include <hip/hip_runtime.h>
#include <stdint.h>

// Problem constants
#define BB 2
#define SS 2048
#define DD 1024
#define HH 16
#define DH 64
#define MM 4096   // BB*SS
#define NQT 32    // SS/64 q-tiles

typedef __attribute__((ext_vector_type(8))) short short8;
typedef __attribute__((ext_vector_type(4))) float floatx4;
typedef unsigned short u16;

#define MFMA16(a,b,c) __builtin_amdgcn_mfma_f32_16x16x32_bf16((a),(b),(c),0,0,0)

__device__ __forceinline__ u16 f2bf(float f) {
  unsigned u = __float_as_uint(f);
  u += 0x7fffu + ((u >> 16) & 1u);
  return (u16)(u >> 16);
}

__device__ __forceinline__ void gll16(const void* g, void* l) {
  __builtin_amdgcn_global_load_lds((const __attribute__((address_space(1))) void*)g,
                                   (__attribute__((address_space(3))) void*)l,
                                   16, 0, 0);
}

// ---------------- sin/cos table: tab[s*32+j] = (sin(s*inv_j), cos(s*inv_j))
__global__ __launch_bounds__(256) void sincos_k(float2* __restrict__ tab) {
  const int t = blockIdx.x * 256 + threadIdx.x;   // S*32 threads
  const int s = t >> 5, j = t & 31;
  const float inv = expf(-(float)j * (0.125f * 2.302585092994046f)); // 10^(-j/8)
  const float a = (float)s * inv;
  tab[t] = make_float2(sinf(a), cosf(a));
}

// ---------------- fp32 -> bf16 converters
__global__ __launch_bounds__(256) void conv_qkv(const float* __restrict__ a, const float* __restrict__ b,
                                                const float* __restrict__ c,
                                                u16* __restrict__ oa, u16* __restrict__ ob, u16* __restrict__ oc) {
  const float* s = blockIdx.y == 0 ? a : (blockIdx.y == 1 ? b : c);
  u16* d = blockIdx.y == 0 ? oa : (blockIdx.y == 1 ? ob : oc);
  const int i = (blockIdx.x * 256 + threadIdx.x) * 4;
  const float4 x = *(const float4*)(s + i);
  ushort4 p; p.x = f2bf(x.x); p.y = f2bf(x.y); p.z = f2bf(x.z); p.w = f2bf(x.w);
  *(ushort4*)(d + i) = p;
}

__global__ __launch_bounds__(256) void conv_w(const float* __restrict__ a, const float* __restrict__ b,
                                              const float* __restrict__ c, const float* __restrict__ d4,
                                              u16* __restrict__ oa, u16* __restrict__ ob,
                                              u16* __restrict__ oc, u16* __restrict__ od) {
  const float* s = blockIdx.y == 0 ? a : (blockIdx.y == 1 ? b : (blockIdx.y == 2 ? c : d4));
  u16* d = blockIdx.y == 0 ? oa : (blockIdx.y == 1 ? ob : (blockIdx.y == 2 ? oc : od));
  const int i = (blockIdx.x * 256 + threadIdx.x) * 4;
  const float4 x = *(const float4*)(s + i);
  ushort4 p; p.x = f2bf(x.x); p.y = f2bf(x.y); p.z = f2bf(x.z); p.w = f2bf(x.w);
  *(ushort4*)(d + i) = p;
}

// ---------------- GEMM body: C[M][N] = A * Bt^T + bias, 128x128 tile, BK=32 (m97 structure)
__device__ __forceinline__ void gemm_body(const u16* __restrict__ A, const u16* __restrict__ Bt,
                                          const float* __restrict__ bias, float* __restrict__ C,
                                          int M, int N, int K, u16* As, u16* Bs) {
  const int tid = threadIdx.x;
  const int w = tid >> 6, l = tid & 63;
  const int lr = l & 15, lq = l >> 4;
  const int m0 = blockIdx.y * 128, n0 = blockIdx.x * 128;
  const int wm = (w >> 1) * 64, wn = (w & 1) * 64;

  floatx4 acc[4][4];
#pragma unroll
  for (int i = 0; i < 4; ++i)
#pragma unroll
    for (int j = 0; j < 4; ++j) acc[i][j] = (floatx4){0.f, 0.f, 0.f, 0.f};

  const int srow = w * 32 + (l >> 2);
  const int scol = (l & 3) * 8;
  const u16* ag = A + (size_t)(m0 + srow) * K + scol;
  const u16* bg = Bt + (size_t)(n0 + srow) * K + scol;
  u16* as0 = &As[w * 1024];
  u16* bs0 = &Bs[w * 1024];

  for (int k0 = 0; k0 < K; k0 += 32) {
    gll16(ag + k0, as0);
    gll16(ag + (size_t)16 * K + k0, as0 + 512);
    gll16(bg + k0, bs0);
    gll16(bg + (size_t)16 * K + k0, bs0 + 512);
    __syncthreads();
    short8 af[4], bfv[4];
#pragma unroll
    for (int i = 0; i < 4; ++i) af[i] = *(const short8*)&As[(wm + i * 16 + lr) * 32 + lq * 8];
#pragma unroll
    for (int j = 0; j < 4; ++j) bfv[j] = *(const short8*)&Bs[(wn + j * 16 + lr) * 32 + lq * 8];
    __builtin_amdgcn_s_setprio(1);
#pragma unroll
    for (int i = 0; i < 4; ++i)
#pragma unroll
      for (int j = 0; j < 4; ++j) acc[i][j] = MFMA16(af[i], bfv[j], acc[i][j]);
    __builtin_amdgcn_s_setprio(0);
    __syncthreads();
  }

#pragma unroll
  for (int i = 0; i < 4; ++i) {
    const int row = m0 + wm + i * 16 + lq * 4;
#pragma unroll
    for (int j = 0; j < 4; ++j) {
      const int col = n0 + wn + j * 16 + lr;
      const float bv = bias[col];
      float* cp = C + (size_t)row * N + col;
#pragma unroll
      for (int r = 0; r < 4; ++r) cp[(size_t)r * N] = acc[i][j][r] + bv;
    }
  }
}

__global__ __launch_bounds__(256) void gemm_bt(const u16* __restrict__ A, const u16* __restrict__ Bt,
                                               const float* __restrict__ bias, float* __restrict__ C,
                                               int M, int N, int K) {
  __shared__ alignas(16) u16 As[128 * 32];
  __shared__ alignas(16) u16 Bs[128 * 32];
  gemm_body(A, Bt, bias, C, M, N, K, As, Bs);
}

// fused q/k/v projections: blockIdx.z selects the problem -> 768 blocks fill the machine
__global__ __launch_bounds__(256) void gemm3(const u16* __restrict__ A0, const u16* __restrict__ A1, const u16* __restrict__ A2,
                                             const u16* __restrict__ B0, const u16* __restrict__ B1, const u16* __restrict__ B2,
                                             const float* __restrict__ c0, const float* __restrict__ c1, const float* __restrict__ c2,
                                             float* __restrict__ C0, float* __restrict__ C1, float* __restrict__ C2) {
  __shared__ alignas(16) u16 As[128 * 32];
  __shared__ alignas(16) u16 Bs[128 * 32];
  const int z = blockIdx.z;
  const u16* A = z == 0 ? A0 : (z == 1 ? A1 : A2);
  const u16* Bt = z == 0 ? B0 : (z == 1 ? B1 : B2);
  const float* bias = z == 0 ? c0 : (z == 1 ? c1 : c2);
  float* C = z == 0 ? C0 : (z == 1 ? C1 : C2);
  gemm_body(A, Bt, bias, C, MM, DD, DD, As, Bs);
}

// ---------------- RoPE + repack: Qlin/Klin fp32 [b*S+s][h*64+e] -> bf16 [b][h][s][64]
__global__ __launch_bounds__(256) void rope_post(const float* __restrict__ Qlin, const float* __restrict__ Klin,
                                                 const float2* __restrict__ tab,
                                                 u16* __restrict__ Qo, u16* __restrict__ Ko) {
  const int t = blockIdx.x * 256 + threadIdx.x;   // MM*DD/2 threads
  const int j = t & 31;
  const int h = (t >> 5) & 15;
  const int row = t >> 9;            // b*S + s
  const int s = row & (SS - 1);
  const int b = row >> 11;
  const float* src = blockIdx.z ? Klin : Qlin;
  u16* dst = blockIdx.z ? Ko : Qo;
  const float2 x = *(const float2*)(src + (size_t)row * DD + h * 64 + 2 * j);
  const float2 sc = tab[s * 32 + j];
  const float e = x.x * sc.x - x.y * sc.y;    //  x1*sin - x2*cos
  const float o = -x.x * sc.y - x.y * sc.x;   // -x1*cos - x2*sin
  const size_t oi = ((size_t)(b * HH + h) * SS + s) * DH + 2 * j;
  ushort2 pk; pk.x = f2bf(e); pk.y = f2bf(o);
  *(ushort2*)(dst + oi) = pk;
}

// ---------------- V: bias already added; fp32 [b*S+s][h*64+e] -> bf16 transposed [bh][e][s]
__global__ __launch_bounds__(256) void v_post(const float* __restrict__ Vlin, u16* __restrict__ Vt) {
  __shared__ alignas(16) u16 tile[64][72];
  const int s0 = blockIdx.x * 64;
  const int bh = blockIdx.y;
  const int b = bh >> 4, h = bh & 15;
  const int t = threadIdx.x;
  const int sr = t >> 4;
  const int e4 = (t & 15) * 4;
#pragma unroll
  for (int it = 0; it < 4; ++it) {
    const int srow = sr + it * 16;
    const float4 x = *(const float4*)(Vlin + ((size_t)(b * SS + s0 + srow)) * DD + h * 64 + e4);
    tile[e4 + 0][srow] = f2bf(x.x);
    tile[e4 + 1][srow] = f2bf(x.y);
    tile[e4 + 2][srow] = f2bf(x.z);
    tile[e4 + 3][srow] = f2bf(x.w);
  }
  __syncthreads();
  const int e = t >> 2;
  const int sc = (t & 3) * 16;
  u16* op = Vt + ((size_t)bh * DH + e) * SS + s0 + sc;
  *(short8*)op = *(const short8*)&tile[e][sc];
  *(short8*)(op + 8) = *(const short8*)&tile[e][sc + 8];
}

// ---------------- causal flash attention
// Q,K bf16 [bh][s][64], V bf16 [bh][64][s] -> O bf16 [b][s][h*64+e]
// Grid: 1D, 1024 blocks. Heavy q-tiles first (qt = 31 - bid/32) so light blocks backfill.
// K,V tiles double-buffered in LDS via global_load_lds with pre-swizzled source
// (XOR swizzle byte^=(row&7)<<4 -> conflict-free ds_read_b128).
__global__ __launch_bounds__(256) void attn_fwd(const u16* __restrict__ Qr, const u16* __restrict__ Kr,
                                                const u16* __restrict__ Vt, u16* __restrict__ O) {
  __shared__ alignas(16) u16 Ks[2][64 * 64];
  __shared__ alignas(16) u16 Vs[2][64 * 64];
  __shared__ alignas(16) u16 P[4][16][72];
  const int bid = blockIdx.x;
  const int qt = (NQT - 1) - (bid >> 5);
  const int bh = bid & 31;
  const int w = threadIdx.x >> 6, l = threadIdx.x & 63;
  const int lr = l & 15, lq = l >> 4;
  const int q0 = qt * 64 + w * 16;
  const u16* Qh = Qr + (size_t)bh * SS * DH;
  const u16* Kh = Kr + (size_t)bh * SS * DH;
  const u16* Vh = Vt + (size_t)bh * DH * SS;

  const short8 qf0 = *(const short8*)(Qh + (size_t)(q0 + lr) * DH + lq * 8);
  const short8 qf1 = *(const short8*)(Qh + (size_t)(q0 + lr) * DH + 32 + lq * 8);

  // staging geometry: wave w stages rows [16w,16w+16) of each 64x64 tile, 2 gll16 per array
  const int srow = w * 16 + (l >> 3);          // c=0 rows; +8 for c=1
  const int scolb = (l & 7) * 16;              // byte col within 128B row
  const int sgofs = ((scolb ^ (((l >> 3) & 7) << 4)) >> 1);  // swizzled source col (u16)

  floatx4 oacc[4];
#pragma unroll
  for (int n = 0; n < 4; ++n) oacc[n] = (floatx4){0.f, 0.f, 0.f, 0.f};
  float mrun[4] = {-1e30f, -1e30f, -1e30f, -1e30f};
  float lrun[4] = {0.f, 0.f, 0.f, 0.f};

  const int swz = (lr & 7) << 4;               // read-side swizzle (byte)

#define STAGE(buf, kv0)                                                                  \
  do {                                                                                   \
    gll16(Kh + (size_t)((kv0) + srow) * DH + sgofs,       &Ks[buf][(w * 16) * 64]);      \
    gll16(Kh + (size_t)((kv0) + srow + 8) * DH + sgofs,   &Ks[buf][(w * 16 + 8) * 64]);  \
    gll16(Vh + (size_t)srow * SS + (kv0) + sgofs,         &Vs[buf][(w * 16) * 64]);      \
    gll16(Vh + (size_t)(srow + 8) * SS + (kv0) + sgofs,   &Vs[buf][(w * 16 + 8) * 64]);  \
  } while (0)

  STAGE(0, 0);
  __syncthreads();

  for (int t = 0; t <= qt; ++t) {
    const int cur = t & 1;
    if (t < qt) STAGE(cur ^ 1, (t + 1) * 64);
    const int kv0 = t * 64;

    floatx4 s[4];
    __builtin_amdgcn_s_setprio(1);
#pragma unroll
    for (int t4 = 0; t4 < 4; ++t4) {
      const int krow = t4 * 16 + lr;
      floatx4 z = (floatx4){0.f, 0.f, 0.f, 0.f};
      z = MFMA16(qf0, *(const short8*)&Ks[cur][krow * 64 + (((lq * 16) ^ swz) >> 1)], z);
      z = MFMA16(qf1, *(const short8*)&Ks[cur][krow * 64 + (((64 + lq * 16) ^ swz) >> 1)], z);
      s[t4] = z;
    }
    __builtin_amdgcn_s_setprio(0);

    if (t == qt) {   // diagonal tile: mask k > q
#pragma unroll
      for (int t4 = 0; t4 < 4; ++t4) {
        const int kcol = kv0 + t4 * 16 + lr;
#pragma unroll
        for (int r = 0; r < 4; ++r)
          if (kcol > q0 + lq * 4 + r) s[t4][r] = -1e30f;
      }
    }

    float scale[4];
#pragma unroll
    for (int r = 0; r < 4; ++r) {
      float mx = fmaxf(fmaxf(s[0][r], s[1][r]), fmaxf(s[2][r], s[3][r]));
      mx = fmaxf(mx, __shfl_xor(mx, 1));
      mx = fmaxf(mx, __shfl_xor(mx, 2));
      mx = fmaxf(mx, __shfl_xor(mx, 4));
      mx = fmaxf(mx, __shfl_xor(mx, 8));
      const float mn = fmaxf(mrun[r], mx);
      scale[r] = __expf(mrun[r] - mn);
      mrun[r] = mn;
      float rs = 0.f;
#pragma unroll
      for (int t4 = 0; t4 < 4; ++t4) {
        const float p = __expf(s[t4][r] - mn);
        s[t4][r] = p;
        rs += p;
      }
      rs += __shfl_xor(rs, 1);
      rs += __shfl_xor(rs, 2);
      rs += __shfl_xor(rs, 4);
      rs += __shfl_xor(rs, 8);
      lrun[r] = lrun[r] * scale[r] + rs;
    }
    const floatx4 sv = {scale[0], scale[1], scale[2], scale[3]};
#pragma unroll
    for (int n = 0; n < 4; ++n) oacc[n] *= sv;
#pragma unroll
    for (int t4 = 0; t4 < 4; ++t4)
#pragma unroll
      for (int r = 0; r < 4; ++r)
        P[w][lq * 4 + r][t4 * 16 + lr] = f2bf(s[t4][r]);

    __builtin_amdgcn_s_setprio(1);
#pragma unroll
    for (int kk = 0; kk < 2; ++kk) {
      const short8 pf = *(const short8*)&P[w][lr][kk * 32 + lq * 8];
#pragma unroll
      for (int n = 0; n < 4; ++n) {
        const int vrow = n * 16 + lr;
        oacc[n] = MFMA16(pf, *(const short8*)&Vs[cur][vrow * 64 + (((kk * 64 + lq * 16) ^ swz) >> 1)], oacc[n]);
      }
    }
    __builtin_amdgcn_s_setprio(0);
    __syncthreads();   // implicit vmcnt drain covers this iter's STAGE; next iter reads cur^1
  }
#undef STAGE

  const int b = bh >> 4, h = bh & 15;
#pragma unroll
  for (int n = 0; n < 4; ++n)
#pragma unroll
    for (int r = 0; r < 4; ++r) {
      const int qrow = q0 + lq * 4 + r;
      const float ov = oacc[n][r] / lrun[r];
      O[((size_t)(b * SS + qrow)) * DD + h * DH + n * 16 + lr] = f2bf(ov);
    }
}

extern "C" void kernel_launch(void* const* d_in, const int* in_sizes, int n_in,
                              void* d_out, int out_size, void* d_ws, size_t ws_size,
                              hipStream_t stream) {
  (void)in_sizes; (void)n_in; (void)out_size; (void)ws_size;
  const float* q  = (const float*)d_in[0];
  const float* k  = (const float*)d_in[1];
  const float* v  = (const float*)d_in[2];
  const float* Wq = (const float*)d_in[3];
  const float* bq = (const float*)d_in[4];
  const float* Wk = (const float*)d_in[5];
  const float* bk = (const float*)d_in[6];
  const float* Wv = (const float*)d_in[7];
  const float* bv = (const float*)d_in[8];
  const float* Wo = (const float*)d_in[9];
  const float* bo = (const float*)d_in[10];
  float* out = (float*)d_out;

  char* ws = (char*)d_ws;
  size_t off = 0;
  auto carve = [&](size_t bytes) { char* p = ws + off; off += (bytes + 255) & ~(size_t)255; return p; };
  u16* qb   = (u16*)carve((size_t)MM * DD * 2);
  u16* kb   = (u16*)carve((size_t)MM * DD * 2);
  u16* vb   = (u16*)carve((size_t)MM * DD * 2);
  u16* wqb  = (u16*)carve((size_t)DD * DD * 2);
  u16* wkb  = (u16*)carve((size_t)DD * DD * 2);
  u16* wvb  = (u16*)carve((size_t)DD * DD * 2);
  u16* wob  = (u16*)carve((size_t)DD * DD * 2);
  float* Qlin = (float*)carve((size_t)MM * DD * 4);
  float* Klin = (float*)carve((size_t)MM * DD * 4);
  float* Vlin = (float*)carve((size_t)MM * DD * 4);
  u16* Vtr  = (u16*)carve((size_t)MM * DD * 2);
  float2* tab = (float2*)carve((size_t)SS * 32 * 8);
  // reuse: after the three projection GEMMs, qb/kb/vb are dead
  u16* Qro = qb;
  u16* Kro = kb;
  u16* Ob  = vb;

  sincos_k<<<SS * 32 / 256, 256, 0, stream>>>(tab);
  conv_qkv<<<dim3(MM * DD / 1024, 3), 256, 0, stream>>>(q, k, v, qb, kb, vb);
  conv_w<<<dim3(DD * DD / 1024, 4), 256, 0, stream>>>(Wq, Wk, Wv, Wo, wqb, wkb, wvb, wob);
  gemm3<<<dim3(DD / 128, MM / 128, 3), 256, 0, stream>>>(qb, kb, vb, wqb, wkb, wvb,
                                                         bq, bk, bv, Qlin, Klin, Vlin);
  rope_post<<<dim3(MM * DD / 2 / 256, 1, 2), 256, 0, stream>>>(Qlin, Klin, tab, Qro, Kro);
  v_post<<<dim3(SS / 64, BB * HH), 256, 0, stream>>>(Vlin, Vtr);
  attn_fwd<<<NQT * BB * HH, 256, 0, stream>>>(Qro, Kro, Vtr, Ob);
  gemm_bt<<<dim3(DD / 128, MM / 128), 256, 0, stream>>>(Ob, wob, bo, out, MM, DD, DD);
}

// Round 3
// 278.706 us; speedup vs baseline: 1.7728x; 1.0329x over previous
//
#include <hip/hip_runtime.h>
#include <stdint.h>

// Problem constants
#define BB 2
#define SS 2048
#define DD 1024
#define HH 16
#define DH 64
#define MM 4096   // BB*SS
#define NQTB 16   // SS/128 q-tiles per (b,h) for attention blocks

typedef __attribute__((ext_vector_type(8))) short short8;
typedef __attribute__((ext_vector_type(4))) float floatx4;
typedef __attribute__((ext_vector_type(16))) float floatx16;
typedef unsigned short u16;

#define MFMA16(a,b,c) __builtin_amdgcn_mfma_f32_16x16x32_bf16((a),(b),(c),0,0,0)
#define MFMA32(a,b,c) __builtin_amdgcn_mfma_f32_32x32x16_bf16((a),(b),(c),0,0,0)

__device__ __forceinline__ u16 f2bf(float f) {
  unsigned u = __float_as_uint(f);
  u += 0x7fffu + ((u >> 16) & 1u);
  return (u16)(u >> 16);
}

__device__ __forceinline__ unsigned cvtpk(float lo, float hi2) {
  unsigned r;
  asm("v_cvt_pk_bf16_f32 %0, %1, %2" : "=v"(r) : "v"(lo), "v"(hi2));
  return r;
}

__device__ __forceinline__ void gll16(const void* g, void* l) {
  __builtin_amdgcn_global_load_lds((const __attribute__((address_space(1))) void*)g,
                                   (__attribute__((address_space(3))) void*)l,
                                   16, 0, 0);
}

// ---------------- sin/cos table: tab[s*32+j] = (sin(s*inv_j), cos(s*inv_j))
__global__ __launch_bounds__(256) void sincos_k(float2* __restrict__ tab) {
  const int t = blockIdx.x * 256 + threadIdx.x;   // S*32 threads
  const int s = t >> 5, j = t & 31;
  const float inv = expf(-(float)j * (0.125f * 2.302585092994046f)); // 10^(-j/8)
  const float a = (float)s * inv;
  tab[t] = make_float2(sinf(a), cosf(a));
}

// ---------------- fp32 -> bf16 converters
__global__ __launch_bounds__(256) void conv_qkv(const float* __restrict__ a, const float* __restrict__ b,
                                                const float* __restrict__ c,
                                                u16* __restrict__ oa, u16* __restrict__ ob, u16* __restrict__ oc) {
  const float* s = blockIdx.y == 0 ? a : (blockIdx.y == 1 ? b : c);
  u16* d = blockIdx.y == 0 ? oa : (blockIdx.y == 1 ? ob : oc);
  const int i = (blockIdx.x * 256 + threadIdx.x) * 4;
  const float4 x = *(const float4*)(s + i);
  ushort4 p; p.x = f2bf(x.x); p.y = f2bf(x.y); p.z = f2bf(x.z); p.w = f2bf(x.w);
  *(ushort4*)(d + i) = p;
}

__global__ __launch_bounds__(256) void conv_w(const float* __restrict__ a, const float* __restrict__ b,
                                              const float* __restrict__ c, const float* __restrict__ d4,
                                              u16* __restrict__ oa, u16* __restrict__ ob,
                                              u16* __restrict__ oc, u16* __restrict__ od) {
  const float* s = blockIdx.y == 0 ? a : (blockIdx.y == 1 ? b : (blockIdx.y == 2 ? c : d4));
  u16* d = blockIdx.y == 0 ? oa : (blockIdx.y == 1 ? ob : (blockIdx.y == 2 ? oc : od));
  const int i = (blockIdx.x * 256 + threadIdx.x) * 4;
  const float4 x = *(const float4*)(s + i);
  ushort4 p; p.x = f2bf(x.x); p.y = f2bf(x.y); p.z = f2bf(x.z); p.w = f2bf(x.w);
  *(ushort4*)(d + i) = p;
}

// ---------------- GEMM body: C[M][N] = A * Bt^T + bias, 128x128 tile, BK=32 (m97 structure)
__device__ __forceinline__ void gemm_body(const u16* __restrict__ A, const u16* __restrict__ Bt,
                                          const float* __restrict__ bias, float* __restrict__ C,
                                          int M, int N, int K, u16* As, u16* Bs) {
  const int tid = threadIdx.x;
  const int w = tid >> 6, l = tid & 63;
  const int lr = l & 15, lq = l >> 4;
  const int m0 = blockIdx.y * 128, n0 = blockIdx.x * 128;
  const int wm = (w >> 1) * 64, wn = (w & 1) * 64;

  floatx4 acc[4][4];
#pragma unroll
  for (int i = 0; i < 4; ++i)
#pragma unroll
    for (int j = 0; j < 4; ++j) acc[i][j] = (floatx4){0.f, 0.f, 0.f, 0.f};

  const int srow = w * 32 + (l >> 2);
  const int scol = (l & 3) * 8;
  const u16* ag = A + (size_t)(m0 + srow) * K + scol;
  const u16* bg = Bt + (size_t)(n0 + srow) * K + scol;
  u16* as0 = &As[w * 1024];
  u16* bs0 = &Bs[w * 1024];

  for (int k0 = 0; k0 < K; k0 += 32) {
    gll16(ag + k0, as0);
    gll16(ag + (size_t)16 * K + k0, as0 + 512);
    gll16(bg + k0, bs0);
    gll16(bg + (size_t)16 * K + k0, bs0 + 512);
    __syncthreads();
    short8 af[4], bfv[4];
#pragma unroll
    for (int i = 0; i < 4; ++i) af[i] = *(const short8*)&As[(wm + i * 16 + lr) * 32 + lq * 8];
#pragma unroll
    for (int j = 0; j < 4; ++j) bfv[j] = *(const short8*)&Bs[(wn + j * 16 + lr) * 32 + lq * 8];
    __builtin_amdgcn_s_setprio(1);
#pragma unroll
    for (int i = 0; i < 4; ++i)
#pragma unroll
      for (int j = 0; j < 4; ++j) acc[i][j] = MFMA16(af[i], bfv[j], acc[i][j]);
    __builtin_amdgcn_s_setprio(0);
    __syncthreads();
  }

#pragma unroll
  for (int i = 0; i < 4; ++i) {
    const int row = m0 + wm + i * 16 + lq * 4;
#pragma unroll
    for (int j = 0; j < 4; ++j) {
      const int col = n0 + wn + j * 16 + lr;
      const float bv = bias[col];
      float* cp = C + (size_t)row * N + col;
#pragma unroll
      for (int r = 0; r < 4; ++r) cp[(size_t)r * N] = acc[i][j][r] + bv;
    }
  }
}

__global__ __launch_bounds__(256) void gemm_bt(const u16* __restrict__ A, const u16* __restrict__ Bt,
                                               const float* __restrict__ bias, float* __restrict__ C,
                                               int M, int N, int K) {
  __shared__ alignas(16) u16 As[128 * 32];
  __shared__ alignas(16) u16 Bs[128 * 32];
  gemm_body(A, Bt, bias, C, M, N, K, As, Bs);
}

// fused q/k/v projections: blockIdx.z selects the problem -> 768 blocks fill the machine
__global__ __launch_bounds__(256) void gemm3(const u16* __restrict__ A0, const u16* __restrict__ A1, const u16* __restrict__ A2,
                                             const u16* __restrict__ B0, const u16* __restrict__ B1, const u16* __restrict__ B2,
                                             const float* __restrict__ c0, const float* __restrict__ c1, const float* __restrict__ c2,
                                             float* __restrict__ C0, float* __restrict__ C1, float* __restrict__ C2) {
  __shared__ alignas(16) u16 As[128 * 32];
  __shared__ alignas(16) u16 Bs[128 * 32];
  const int z = blockIdx.z;
  const u16* A = z == 0 ? A0 : (z == 1 ? A1 : A2);
  const u16* Bt = z == 0 ? B0 : (z == 1 ? B1 : B2);
  const float* bias = z == 0 ? c0 : (z == 1 ? c1 : c2);
  float* C = z == 0 ? C0 : (z == 1 ? C1 : C2);
  gemm_body(A, Bt, bias, C, MM, DD, DD, As, Bs);
}

// ---------------- RoPE + repack: Qlin/Klin fp32 [b*S+s][h*64+e] -> bf16 [b][h][s][64]
__global__ __launch_bounds__(256) void rope_post(const float* __restrict__ Qlin, const float* __restrict__ Klin,
                                                 const float2* __restrict__ tab,
                                                 u16* __restrict__ Qo, u16* __restrict__ Ko) {
  const int t = blockIdx.x * 256 + threadIdx.x;   // MM*DD/2 threads
  const int j = t & 31;
  const int h = (t >> 5) & 15;
  const int row = t >> 9;            // b*S + s
  const int s = row & (SS - 1);
  const int b = row >> 11;
  const float* src = blockIdx.z ? Klin : Qlin;
  u16* dst = blockIdx.z ? Ko : Qo;
  const float2 x = *(const float2*)(src + (size_t)row * DD + h * 64 + 2 * j);
  const float2 sc = tab[s * 32 + j];
  const float e = x.x * sc.x - x.y * sc.y;    //  x1*sin - x2*cos
  const float o = -x.x * sc.y - x.y * sc.x;   // -x1*cos - x2*sin
  const size_t oi = ((size_t)(b * HH + h) * SS + s) * DH + 2 * j;
  ushort2 pk; pk.x = f2bf(e); pk.y = f2bf(o);
  *(ushort2*)(dst + oi) = pk;
}

// ---------------- V: bias already added; fp32 [b*S+s][h*64+e] -> bf16 transposed [bh][e][s]
__global__ __launch_bounds__(256) void v_post(const float* __restrict__ Vlin, u16* __restrict__ Vt) {
  __shared__ alignas(16) u16 tile[64][72];
  const int s0 = blockIdx.x * 64;
  const int bh = blockIdx.y;
  const int b = bh >> 4, h = bh & 15;
  const int t = threadIdx.x;
  const int sr = t >> 4;
  const int e4 = (t & 15) * 4;
#pragma unroll
  for (int it = 0; it < 4; ++it) {
    const int srow = sr + it * 16;
    const float4 x = *(const float4*)(Vlin + ((size_t)(b * SS + s0 + srow)) * DD + h * 64 + e4);
    tile[e4 + 0][srow] = f2bf(x.x);
    tile[e4 + 1][srow] = f2bf(x.y);
    tile[e4 + 2][srow] = f2bf(x.z);
    tile[e4 + 3][srow] = f2bf(x.w);
  }
  __syncthreads();
  const int e = t >> 2;
  const int sc = (t & 3) * 16;
  u16* op = Vt + ((size_t)bh * DH + e) * SS + s0 + sc;
  *(short8*)op = *(const short8*)&tile[e][sc];
  *(short8*)(op + 8) = *(const short8*)&tile[e][sc + 8];
}

// ---------------- causal flash attention, swapped-operand 32x32 structure
// Q,K bf16 [bh][s][64], V bf16 [bh][64][s] -> O bf16 [b][s][h*64+e]
// S^T = mfma(K, Q): col=q (lane&31), row=kv -> softmax reduce is in-lane + 1 shfl(32).
// P stays in registers (cvt_pk + lane^32 exchange); O^T = mfma(V^T, P^T): col=q aligns
// rescale/divide with the lane's running m/l. 4 waves x 32 q-rows = 128 q/block.
__global__ __launch_bounds__(256) void attn_fwd(const u16* __restrict__ Qr, const u16* __restrict__ Kr,
                                                const u16* __restrict__ Vt, u16* __restrict__ O) {
  __shared__ alignas(16) u16 Ks[2][64 * 64];
  __shared__ alignas(16) u16 Vs[2][64 * 64];
  const int bid = blockIdx.x;
  const int qt = (NQTB - 1) - (bid >> 5);      // heavy q-tiles first
  const int bh = bid & 31;
  const int w = threadIdx.x >> 6, l = threadIdx.x & 63;
  const int ql = l & 31, hi = l >> 5;
  const int qw0 = qt * 128 + w * 32;           // this wave's 32 q rows
  const u16* Qh = Qr + (size_t)bh * SS * DH;
  const u16* Kh = Kr + (size_t)bh * SS * DH;
  const u16* Vh = Vt + (size_t)bh * DH * SS;

  // Q B-fragments: lane holds q = qw0+ql, d = i*16 + hi*8 .. +7
  short8 qf[4];
#pragma unroll
  for (int i = 0; i < 4; ++i)
    qf[i] = *(const short8*)(Qh + (size_t)(qw0 + ql) * DH + i * 16 + hi * 8);

  floatx16 oacc[2];
#pragma unroll
  for (int dt = 0; dt < 2; ++dt)
#pragma unroll
    for (int r = 0; r < 16; ++r) oacc[dt][r] = 0.f;
  float mrun = -1e30f, lrun = 0.f;

  // staging geometry: wave w stages rows [16w,16w+16) of each 64x(64x2B) tile
  const int srow = w * 16 + (l >> 3);
  const int sgofs = ((((l & 7) * 16) ^ (((l >> 3) & 7) << 4)) >> 1);   // swizzled src col (u16)
  const int swzb = (ql & 7) << 4;              // read-side swizzle (byte)

#define STAGE(buf, kv0)                                                                  \
  do {                                                                                   \
    gll16(Kh + (size_t)((kv0) + srow) * DH + sgofs,       &Ks[buf][(w * 16) * 64]);      \
    gll16(Kh + (size_t)((kv0) + srow + 8) * DH + sgofs,   &Ks[buf][(w * 16 + 8) * 64]);  \
    gll16(Vh + (size_t)srow * SS + (kv0) + sgofs,         &Vs[buf][(w * 16) * 64]);      \
    gll16(Vh + (size_t)(srow + 8) * SS + (kv0) + sgofs,   &Vs[buf][(w * 16 + 8) * 64]);  \
  } while (0)

  const int T = 2 * qt + 2;
  STAGE(0, 0);
  __syncthreads();

  for (int t = 0; t < T; ++t) {
    const int cur = t & 1;
    if (t < T - 1) STAGE(cur ^ 1, (t + 1) * 64);
    const int kv0 = t * 64;

    if (kv0 <= qw0 + 31) {                     // wave-level causal skip (barrier stays uniform)
      // ---- S^T = K · Q^T  (rows=kv, cols=q)
      floatx16 st[2];
#pragma unroll
      for (int tt = 0; tt < 2; ++tt)
#pragma unroll
        for (int r = 0; r < 16; ++r) st[tt][r] = 0.f;
      __builtin_amdgcn_s_setprio(1);
#pragma unroll
      for (int tt = 0; tt < 2; ++tt)
#pragma unroll
        for (int i = 0; i < 4; ++i) {
          const u16* kp = &Ks[cur][(tt * 32 + ql) * 64 + (((32 * i + 16 * hi) ^ swzb) >> 1)];
          st[tt] = MFMA32(*(const short8*)kp, qf[i], st[tt]);
        }
      __builtin_amdgcn_s_setprio(0);

      if (kv0 + 63 > qw0) {                    // diagonal: mask kv > q
#pragma unroll
        for (int tt = 0; tt < 2; ++tt)
#pragma unroll
          for (int r = 0; r < 16; ++r) {
            const int kv = kv0 + tt * 32 + (r & 3) + 8 * (r >> 2) + 4 * hi;
            if (kv > qw0 + ql) st[tt][r] = -1e30f;
          }
      }

      // ---- online softmax, lane-local over 32 kv + one shfl(32)
      floatx16 mx;
#pragma unroll
      for (int r = 0; r < 16; ++r) mx[r] = fmaxf(st[0][r], st[1][r]);
      float m8[8];
#pragma unroll
      for (int r = 0; r < 8; ++r) m8[r] = fmaxf(mx[r], mx[r + 8]);
      float m4a = fmaxf(m8[0], m8[4]), m4b = fmaxf(m8[1], m8[5]);
      float m4c = fmaxf(m8[2], m8[6]), m4d = fmaxf(m8[3], m8[7]);
      float tmax = fmaxf(fmaxf(m4a, m4b), fmaxf(m4c, m4d));
      tmax = fmaxf(tmax, __shfl_xor(tmax, 32));
      const float mn = fmaxf(mrun, tmax);
      const float sc = __expf(mrun - mn);
      mrun = mn;
      float ps = 0.f;
#pragma unroll
      for (int tt = 0; tt < 2; ++tt)
#pragma unroll
        for (int r = 0; r < 16; ++r) {
          const float p = __expf(st[tt][r] - mn);
          st[tt][r] = p;
          ps += p;
        }
      ps += __shfl_xor(ps, 32);
      lrun = lrun * sc + ps;
#pragma unroll
      for (int dt = 0; dt < 2; ++dt)
#pragma unroll
        for (int r = 0; r < 16; ++r) oacc[dt][r] *= sc;

      // ---- pack P^T into PV B-fragments (in-register, lane^32 exchange)
      short8 pfrag[4];
#pragma unroll
      for (int c = 0; c < 4; ++c) {
        const int tt = c >> 1;
        const int A0 = 2 * (c & 1), A1 = A0 + 1;
        const unsigned P00 = cvtpk(st[tt][4 * A0 + 0], st[tt][4 * A0 + 1]);
        const unsigned P01 = cvtpk(st[tt][4 * A0 + 2], st[tt][4 * A0 + 3]);
        const unsigned P10 = cvtpk(st[tt][4 * A1 + 0], st[tt][4 * A1 + 1]);
        const unsigned P11 = cvtpk(st[tt][4 * A1 + 2], st[tt][4 * A1 + 3]);
        const unsigned S0 = hi ? P00 : P10;    // send: a = 2(c&1) + (1-hi)
        const unsigned S1 = hi ? P01 : P11;
        const unsigned R0 = (unsigned)__shfl_xor((int)S0, 32);
        const unsigned R1 = (unsigned)__shfl_xor((int)S1, 32);
        union { unsigned u[4]; short8 s; } fd;
        fd.u[0] = hi ? R0 : P00;
        fd.u[1] = hi ? R1 : P01;
        fd.u[2] = hi ? P10 : R0;
        fd.u[3] = hi ? P11 : R1;
        pfrag[c] = fd.s;
      }

      // ---- O^T += V^T · P^T  (rows=d, cols=q)
      __builtin_amdgcn_s_setprio(1);
#pragma unroll
      for (int dt = 0; dt < 2; ++dt)
#pragma unroll
        for (int c = 0; c < 4; ++c) {
          const u16* vp = &Vs[cur][(dt * 32 + ql) * 64 + (((32 * c + 16 * hi) ^ swzb) >> 1)];
          oacc[dt] = MFMA32(*(const short8*)vp, pfrag[c], oacc[dt]);
        }
      __builtin_amdgcn_s_setprio(0);
    }
    __syncthreads();   // drains this iter's STAGE (implicit vmcnt); next iter reads cur^1
  }
#undef STAGE

  // ---- epilogue: lane owns q = qw0+ql entirely; d = dt*32 + 8g + 4hi + b4
  const float inv = 1.0f / lrun;
  const int b = bh >> 4, h = bh & 15;
  u16* orow = O + ((size_t)(b * SS + qw0 + ql)) * DD + h * DH;
#pragma unroll
  for (int dt = 0; dt < 2; ++dt)
#pragma unroll
    for (int g = 0; g < 4; ++g) {
      ushort4 pk;
      pk.x = f2bf(oacc[dt][4 * g + 0] * inv);
      pk.y = f2bf(oacc[dt][4 * g + 1] * inv);
      pk.z = f2bf(oacc[dt][4 * g + 2] * inv);
      pk.w = f2bf(oacc[dt][4 * g + 3] * inv);
      *(ushort4*)(orow + dt * 32 + 8 * g + 4 * hi) = pk;
    }
}

extern "C" void kernel_launch(void* const* d_in, const int* in_sizes, int n_in,
                              void* d_out, int out_size, void* d_ws, size_t ws_size,
                              hipStream_t stream) {
  (void)in_sizes; (void)n_in; (void)out_size; (void)ws_size;
  const float* q  = (const float*)d_in[0];
  const float* k  = (const float*)d_in[1];
  const float* v  = (const float*)d_in[2];
  const float* Wq = (const float*)d_in[3];
  const float* bq = (const float*)d_in[4];
  const float* Wk = (const float*)d_in[5];
  const float* bk = (const float*)d_in[6];
  const float* Wv = (const float*)d_in[7];
  const float* bv = (const float*)d_in[8];
  const float* Wo = (const float*)d_in[9];
  const float* bo = (const float*)d_in[10];
  float* out = (float*)d_out;

  char* ws = (char*)d_ws;
  size_t off = 0;
  auto carve = [&](size_t bytes) { char* p = ws + off; off += (bytes + 255) & ~(size_t)255; return p; };
  u16* qb   = (u16*)carve((size_t)MM * DD * 2);
  u16* kb   = (u16*)carve((size_t)MM * DD * 2);
  u16* vb   = (u16*)carve((size_t)MM * DD * 2);
  u16* wqb  = (u16*)carve((size_t)DD * DD * 2);
  u16* wkb  = (u16*)carve((size_t)DD * DD * 2);
  u16* wvb  = (u16*)carve((size_t)DD * DD * 2);
  u16* wob  = (u16*)carve((size_t)DD * DD * 2);
  float* Qlin = (float*)carve((size_t)MM * DD * 4);
  float* Klin = (float*)carve((size_t)MM * DD * 4);
  float* Vlin = (float*)carve((size_t)MM * DD * 4);
  u16* Vtr  = (u16*)carve((size_t)MM * DD * 2);
  float2* tab = (float2*)carve((size_t)SS * 32 * 8);
  // reuse: after the three projection GEMMs, qb/kb/vb are dead
  u16* Qro = qb;
  u16* Kro = kb;
  u16* Ob  = vb;

  sincos_k<<<SS * 32 / 256, 256, 0, stream>>>(tab);
  conv_qkv<<<dim3(MM * DD / 1024, 3), 256, 0, stream>>>(q, k, v, qb, kb, vb);
  conv_w<<<dim3(DD * DD / 1024, 4), 256, 0, stream>>>(Wq, Wk, Wv, Wo, wqb, wkb, wvb, wob);
  gemm3<<<dim3(DD / 128, MM / 128, 3), 256, 0, stream>>>(qb, kb, vb, wqb, wkb, wvb,
                                                         bq, bk, bv, Qlin, Klin, Vlin);
  rope_post<<<dim3(MM * DD / 2 / 256, 1, 2), 256, 0, stream>>>(Qlin, Klin, tab, Qro, Kro);
  v_post<<<dim3(SS / 64, BB * HH), 256, 0, stream>>>(Vlin, Vtr);
  attn_fwd<<<NQTB * BB * HH, 256, 0, stream>>>(Qro, Kro, Vtr, Ob);
  gemm_bt<<<dim3(DD / 128, MM / 128), 256, 0, stream>>>(Ob, wob, bo, out, MM, DD, DD);
}

// Round 5
// 269.084 us; speedup vs baseline: 1.8362x; 1.0358x over previous
//
#include <hip/hip_runtime.h>
#include <stdint.h>

// Problem constants
#define BB 2
#define SS 2048
#define DD 1024
#define HH 16
#define DH 64
#define MM 4096   // BB*SS

typedef __attribute__((ext_vector_type(8))) short short8;
typedef __attribute__((ext_vector_type(4))) float floatx4;
typedef __attribute__((ext_vector_type(16))) float floatx16;
typedef unsigned short u16;

#define MFMA16(a,b,c) __builtin_amdgcn_mfma_f32_16x16x32_bf16((a),(b),(c),0,0,0)
#define MFMA32(a,b,c) __builtin_amdgcn_mfma_f32_32x32x16_bf16((a),(b),(c),0,0,0)

__device__ __forceinline__ u16 f2bf(float f) {
  unsigned u = __float_as_uint(f);
  u += 0x7fffu + ((u >> 16) & 1u);
  return (u16)(u >> 16);
}

__device__ __forceinline__ unsigned cvtpk(float lo, float hi2) {
  unsigned r;
  asm("v_cvt_pk_bf16_f32 %0, %1, %2" : "=v"(r) : "v"(lo), "v"(hi2));
  return r;
}

__device__ __forceinline__ void gll16(const void* g, void* l) {
  __builtin_amdgcn_global_load_lds((const __attribute__((address_space(1))) void*)g,
                                   (__attribute__((address_space(3))) void*)l,
                                   16, 0, 0);
}

// ---------------- sin/cos table: tab[s*32+j] = (sin(s*inv_j), cos(s*inv_j))
__global__ __launch_bounds__(256) void sincos_k(float2* __restrict__ tab) {
  const int t = blockIdx.x * 256 + threadIdx.x;   // S*32 threads
  const int s = t >> 5, j = t & 31;
  const float inv = expf(-(float)j * (0.125f * 2.302585092994046f)); // 10^(-j/8)
  const float a = (float)s * inv;
  tab[t] = make_float2(sinf(a), cosf(a));
}

// ---------------- fp32 -> bf16 converters
__global__ __launch_bounds__(256) void conv_qkv(const float* __restrict__ a, const float* __restrict__ b,
                                                const float* __restrict__ c,
                                                u16* __restrict__ oa, u16* __restrict__ ob, u16* __restrict__ oc) {
  const float* s = blockIdx.y == 0 ? a : (blockIdx.y == 1 ? b : c);
  u16* d = blockIdx.y == 0 ? oa : (blockIdx.y == 1 ? ob : oc);
  const int i = (blockIdx.x * 256 + threadIdx.x) * 4;
  const float4 x = *(const float4*)(s + i);
  ushort4 p; p.x = f2bf(x.x); p.y = f2bf(x.y); p.z = f2bf(x.z); p.w = f2bf(x.w);
  *(ushort4*)(d + i) = p;
}

__global__ __launch_bounds__(256) void conv_w(const float* __restrict__ a, const float* __restrict__ b,
                                              const float* __restrict__ c, const float* __restrict__ d4,
                                              u16* __restrict__ oa, u16* __restrict__ ob,
                                              u16* __restrict__ oc, u16* __restrict__ od) {
  const float* s = blockIdx.y == 0 ? a : (blockIdx.y == 1 ? b : (blockIdx.y == 2 ? c : d4));
  u16* d = blockIdx.y == 0 ? oa : (blockIdx.y == 1 ? ob : (blockIdx.y == 2 ? oc : od));
  const int i = (blockIdx.x * 256 + threadIdx.x) * 4;
  const float4 x = *(const float4*)(s + i);
  ushort4 p; p.x = f2bf(x.x); p.y = f2bf(x.y); p.z = f2bf(x.z); p.w = f2bf(x.w);
  *(ushort4*)(d + i) = p;
}

// ---------------- GEMM core: 64x128 tile, BK=32, 4 waves 2x2 (wave = 32x64)
// acc[i<2][j<4]; row = m0 + (w>>1)*32 + i*16 + lq*4 + r; col = n0 + (w&1)*64 + j*16 + lr
__device__ __forceinline__ void gemm_core64(const u16* __restrict__ A, const u16* __restrict__ Bt,
                                            int K, u16* As, u16* Bs, floatx4 acc[2][4],
                                            int m0, int n0) {
  const int tid = threadIdx.x;
  const int w = tid >> 6, l = tid & 63;
  const int lr = l & 15, lq = l >> 4;
  const int wm = (w >> 1) * 32, wn = (w & 1) * 64;

#pragma unroll
  for (int i = 0; i < 2; ++i)
#pragma unroll
    for (int j = 0; j < 4; ++j) acc[i][j] = (floatx4){0.f, 0.f, 0.f, 0.f};

  const int arow = w * 16 + (l >> 2);   // A stage: wave w covers 16 rows
  const int brow = w * 32 + (l >> 2);   // B stage: wave w covers 32 rows (2 chunks)
  const int scol = (l & 3) * 8;
  const u16* ag = A + (size_t)(m0 + arow) * K + scol;
  const u16* bg = Bt + (size_t)(n0 + brow) * K + scol;
  u16* as0 = &As[w * 512];
  u16* bs0 = &Bs[w * 1024];

  for (int k0 = 0; k0 < K; k0 += 32) {
    gll16(ag + k0, as0);
    gll16(bg + k0, bs0);
    gll16(bg + (size_t)16 * K + k0, bs0 + 512);
    __syncthreads();
    short8 af[2], bfv[4];
#pragma unroll
    for (int i = 0; i < 2; ++i) af[i] = *(const short8*)&As[(wm + i * 16 + lr) * 32 + lq * 8];
#pragma unroll
    for (int j = 0; j < 4; ++j) bfv[j] = *(const short8*)&Bs[(wn + j * 16 + lr) * 32 + lq * 8];
    __builtin_amdgcn_s_setprio(1);
#pragma unroll
    for (int i = 0; i < 2; ++i)
#pragma unroll
      for (int j = 0; j < 4; ++j) acc[i][j] = MFMA16(af[i], bfv[j], acc[i][j]);
    __builtin_amdgcn_s_setprio(0);
    __syncthreads();
  }
}

// fused q/k/v projections + RoPE/pack (z=0 Q, z=1 K) or V-transpose (z=2).
__global__ __launch_bounds__(256) void gemm3_fused(
    const u16* __restrict__ A0, const u16* __restrict__ A1, const u16* __restrict__ A2,
    const u16* __restrict__ B0, const u16* __restrict__ B1, const u16* __restrict__ B2,
    const float* __restrict__ c0, const float* __restrict__ c1, const float* __restrict__ c2,
    u16* __restrict__ Qro, u16* __restrict__ Kro, u16* __restrict__ Vtr,
    const float2* __restrict__ tab) {
  __shared__ alignas(16) u16 As[64 * 32];
  __shared__ alignas(16) u16 Bs[128 * 32];
  const int z = blockIdx.z;
  const u16* A = z == 0 ? A0 : (z == 1 ? A1 : A2);
  const u16* Bt = z == 0 ? B0 : (z == 1 ? B1 : B2);
  const float* bias = z == 0 ? c0 : (z == 1 ? c1 : c2);
  const int m0 = blockIdx.y * 64, n0 = blockIdx.x * 128;

  floatx4 acc[2][4];
  gemm_core64(A, Bt, DD, As, Bs, acc, m0, n0);

  const int tid = threadIdx.x;
  const int w = tid >> 6, l = tid & 63;
  const int lr = l & 15, lq = l >> 4;
  const int wm = (w >> 1) * 32, wn = (w & 1) * 64;

  if (z == 2) {
    // V^T: Vt[((b*16+h)*64 + e)*SS + s], bias added, bf16
#pragma unroll
    for (int i = 0; i < 2; ++i) {
      const int row = m0 + wm + i * 16 + lq * 4;   // 4 consecutive s from here
      const int b = row >> 11, s = row & (SS - 1);
#pragma unroll
      for (int j = 0; j < 4; ++j) {
        const int col = n0 + wn + j * 16 + lr;
        const int h = col >> 6, e = col & 63;
        const float bv = bias[col];
        ushort4 pk;
        pk.x = f2bf(acc[i][j][0] + bv);
        pk.y = f2bf(acc[i][j][1] + bv);
        pk.z = f2bf(acc[i][j][2] + bv);
        pk.w = f2bf(acc[i][j][3] + bv);
        *(ushort4*)(Vtr + ((size_t)(b * HH + h) * DH + e) * SS + s) = pk;
      }
    }
  } else {
    u16* dst = z ? Kro : Qro;
#pragma unroll
    for (int i = 0; i < 2; ++i) {
#pragma unroll
      for (int j = 0; j < 4; ++j) {
        const int col = n0 + wn + j * 16 + lr;
        const int h = col >> 6, e = col & 63;
        const float bv = bias[col];
#pragma unroll
        for (int r = 0; r < 4; ++r) {
          const int row = m0 + wm + i * 16 + lq * 4 + r;
          const int b = row >> 11, s = row & (SS - 1);
          const float v = acc[i][j][r] + bv;
          const float p = __shfl_xor(v, 1);     // even/odd partner (col^1 <-> lane^1)
          const float2 sc = tab[s * 32 + (e >> 1)];
          const float ov = ((e & 1) == 0) ? (v * sc.x - p * sc.y)     //  x1*sin - x2*cos
                                          : (-p * sc.y - v * sc.x);   // -x1*cos - x2*sin
          dst[((size_t)(b * HH + h) * SS + s) * DH + e] = f2bf(ov);
        }
      }
    }
  }
}

// out-projection: C fp32 = A(bf16) * Bt^T + bias
__global__ __launch_bounds__(256) void gemm_bt(const u16* __restrict__ A, const u16* __restrict__ Bt,
                                               const float* __restrict__ bias, float* __restrict__ C,
                                               int M, int N, int K) {
  __shared__ alignas(16) u16 As[64 * 32];
  __shared__ alignas(16) u16 Bs[128 * 32];
  const int m0 = blockIdx.y * 64, n0 = blockIdx.x * 128;
  floatx4 acc[2][4];
  gemm_core64(A, Bt, K, As, Bs, acc, m0, n0);

  const int tid = threadIdx.x;
  const int w = tid >> 6, l = tid & 63;
  const int lr = l & 15, lq = l >> 4;
  const int wm = (w >> 1) * 32, wn = (w & 1) * 64;
#pragma unroll
  for (int i = 0; i < 2; ++i) {
    const int row = m0 + wm + i * 16 + lq * 4;
#pragma unroll
    for (int j = 0; j < 4; ++j) {
      const int col = n0 + wn + j * 16 + lr;
      const float bv = bias[col];
      float* cp = C + (size_t)row * N + col;
#pragma unroll
      for (int r = 0; r < 4; ++r) cp[(size_t)r * N] = acc[i][j][r] + bv;
    }
  }
}

// ---------------- causal flash attention, swapped-operand 32x32, 2 waves x 32 q = 64 q/block
// Q,K bf16 [bh][s][64]; V bf16 [bh][64][s]; O bf16 [b][s][h*64+e]
// S^T = mfma(K, Q): col=q (lane&31) -> softmax lane-local + 1 shfl(32). R3 numerics
// (natural domain __expf, rescale every tile) — proven margin.
__global__ __launch_bounds__(128) void attn_fwd(const u16* __restrict__ Qr, const u16* __restrict__ Kr,
                                                const u16* __restrict__ Vt, u16* __restrict__ O) {
  __shared__ alignas(16) u16 Ks[2][64 * 64];
  __shared__ alignas(16) u16 Vs[2][64 * 64];
  const int bid = blockIdx.x;
  const int qt = 31 - (bid >> 5);              // heavy q-tiles first
  const int bh = bid & 31;
  const int w = threadIdx.x >> 6, l = threadIdx.x & 63;
  const int ql = l & 31, hi = l >> 5;
  const int qw0 = qt * 64 + w * 32;            // this wave's 32 q rows
  const u16* Qh = Qr + (size_t)bh * SS * DH;
  const u16* Kh = Kr + (size_t)bh * SS * DH;
  const u16* Vh = Vt + (size_t)bh * DH * SS;

  short8 qf[4];
#pragma unroll
  for (int i = 0; i < 4; ++i)
    qf[i] = *(const short8*)(Qh + (size_t)(qw0 + ql) * DH + i * 16 + hi * 8);

  floatx16 oacc[2];
#pragma unroll
  for (int dt = 0; dt < 2; ++dt)
#pragma unroll
    for (int r = 0; r < 16; ++r) oacc[dt][r] = 0.f;
  float mrun = -1e30f, lrun = 0.f;

  // staging: wave w covers rows [w*32, w*32+32) of each 64x(64 u16) tile, 4 gll16 per array
  const int srow = w * 32 + (l >> 3);
  const int sgofs = ((((l & 7) * 16) ^ (((l >> 3) & 7) << 4)) >> 1);   // swizzled src col (u16)
  const int swzb = (ql & 7) << 4;              // read-side swizzle (byte)

#define STAGE(buf, kv0)                                                                    \
  do {                                                                                     \
    gll16(Kh + (size_t)((kv0) + srow) * DH + sgofs,        &Ks[buf][(w * 32) * 64]);       \
    gll16(Kh + (size_t)((kv0) + srow + 8) * DH + sgofs,    &Ks[buf][(w * 32 + 8) * 64]);   \
    gll16(Kh + (size_t)((kv0) + srow + 16) * DH + sgofs,   &Ks[buf][(w * 32 + 16) * 64]);  \
    gll16(Kh + (size_t)((kv0) + srow + 24) * DH + sgofs,   &Ks[buf][(w * 32 + 24) * 64]);  \
    gll16(Vh + (size_t)srow * SS + (kv0) + sgofs,          &Vs[buf][(w * 32) * 64]);       \
    gll16(Vh + (size_t)(srow + 8) * SS + (kv0) + sgofs,    &Vs[buf][(w * 32 + 8) * 64]);   \
    gll16(Vh + (size_t)(srow + 16) * SS + (kv0) + sgofs,   &Vs[buf][(w * 32 + 16) * 64]);  \
    gll16(Vh + (size_t)(srow + 24) * SS + (kv0) + sgofs,   &Vs[buf][(w * 32 + 24) * 64]);  \
  } while (0)

  const int T = qt + 1;
  STAGE(0, 0);
  __syncthreads();

  for (int t = 0; t < T; ++t) {
    const int cur = t & 1;
    if (t < T - 1) STAGE(cur ^ 1, (t + 1) * 64);
    const int kv0 = t * 64;

    // ---- S^T = K · Q^T  (rows=kv, cols=q)
    floatx16 st[2];
#pragma unroll
    for (int tt = 0; tt < 2; ++tt)
#pragma unroll
      for (int r = 0; r < 16; ++r) st[tt][r] = 0.f;
    __builtin_amdgcn_s_setprio(1);
#pragma unroll
    for (int tt = 0; tt < 2; ++tt)
#pragma unroll
      for (int i = 0; i < 4; ++i) {
        const u16* kp = &Ks[cur][(tt * 32 + ql) * 64 + (((32 * i + 16 * hi) ^ swzb) >> 1)];
        st[tt] = MFMA32(*(const short8*)kp, qf[i], st[tt]);
      }
    __builtin_amdgcn_s_setprio(0);

    if (t == T - 1) {                          // diagonal: mask kv > q
#pragma unroll
      for (int tt = 0; tt < 2; ++tt)
#pragma unroll
        for (int r = 0; r < 16; ++r) {
          const int kv = kv0 + tt * 32 + (r & 3) + 8 * (r >> 2) + 4 * hi;
          if (kv > qw0 + ql) st[tt][r] = -1e30f;
        }
    }

    // ---- online softmax: lane-local max over 32 kv + one shfl(32); rescale every tile
    floatx16 mx;
#pragma unroll
    for (int r = 0; r < 16; ++r) mx[r] = fmaxf(st[0][r], st[1][r]);
    float m8[8];
#pragma unroll
    for (int r = 0; r < 8; ++r) m8[r] = fmaxf(mx[r], mx[r + 8]);
    float m4a = fmaxf(m8[0], m8[4]), m4b = fmaxf(m8[1], m8[5]);
    float m4c = fmaxf(m8[2], m8[6]), m4d = fmaxf(m8[3], m8[7]);
    float tmax = fmaxf(fmaxf(m4a, m4b), fmaxf(m4c, m4d));
    tmax = fmaxf(tmax, __shfl_xor(tmax, 32));

    const float mn = fmaxf(mrun, tmax);
    const float sc = __expf(mrun - mn);
    mrun = mn;
    float ps = 0.f;
#pragma unroll
    for (int tt = 0; tt < 2; ++tt)
#pragma unroll
      for (int r = 0; r < 16; ++r) {
        const float p = __expf(st[tt][r] - mn);
        st[tt][r] = p;
        ps += p;
      }
    ps += __shfl_xor(ps, 32);
    lrun = lrun * sc + ps;
#pragma unroll
    for (int dt = 0; dt < 2; ++dt)
#pragma unroll
      for (int r = 0; r < 16; ++r) oacc[dt][r] *= sc;

    // ---- pack P^T into PV B-fragments (in-register, lane^32 exchange)
    short8 pfrag[4];
#pragma unroll
    for (int c = 0; c < 4; ++c) {
      const int tt = c >> 1;
      const int A0r = 2 * (c & 1), A1r = A0r + 1;
      const unsigned P00 = cvtpk(st[tt][4 * A0r + 0], st[tt][4 * A0r + 1]);
      const unsigned P01 = cvtpk(st[tt][4 * A0r + 2], st[tt][4 * A0r + 3]);
      const unsigned P10 = cvtpk(st[tt][4 * A1r + 0], st[tt][4 * A1r + 1]);
      const unsigned P11 = cvtpk(st[tt][4 * A1r + 2], st[tt][4 * A1r + 3]);
      const unsigned S0 = hi ? P00 : P10;
      const unsigned S1 = hi ? P01 : P11;
      const unsigned R0 = (unsigned)__shfl_xor((int)S0, 32);
      const unsigned R1 = (unsigned)__shfl_xor((int)S1, 32);
      union { unsigned u[4]; short8 s; } fd;
      fd.u[0] = hi ? R0 : P00;
      fd.u[1] = hi ? R1 : P01;
      fd.u[2] = hi ? P10 : R0;
      fd.u[3] = hi ? P11 : R1;
      pfrag[c] = fd.s;
    }

    // ---- O^T += V^T · P^T  (rows=d, cols=q)
    __builtin_amdgcn_s_setprio(1);
#pragma unroll
    for (int dt = 0; dt < 2; ++dt)
#pragma unroll
      for (int c = 0; c < 4; ++c) {
        const u16* vp = &Vs[cur][(dt * 32 + ql) * 64 + (((32 * c + 16 * hi) ^ swzb) >> 1)];
        oacc[dt] = MFMA32(*(const short8*)vp, pfrag[c], oacc[dt]);
      }
    __builtin_amdgcn_s_setprio(0);
    __syncthreads();   // drains this iter's STAGE (implicit vmcnt); next iter reads cur^1
  }
#undef STAGE

  // ---- epilogue: lane owns q = qw0+ql; d = dt*32 + 8g + 4hi + 0..3
  const float inv = 1.0f / lrun;
  const int b = bh >> 4, h = bh & 15;
  u16* orow = O + ((size_t)(b * SS + qw0 + ql)) * DD + h * DH;
#pragma unroll
  for (int dt = 0; dt < 2; ++dt)
#pragma unroll
    for (int g = 0; g < 4; ++g) {
      ushort4 pk;
      pk.x = f2bf(oacc[dt][4 * g + 0] * inv);
      pk.y = f2bf(oacc[dt][4 * g + 1] * inv);
      pk.z = f2bf(oacc[dt][4 * g + 2] * inv);
      pk.w = f2bf(oacc[dt][4 * g + 3] * inv);
      *(ushort4*)(orow + dt * 32 + 8 * g + 4 * hi) = pk;
    }
}

extern "C" void kernel_launch(void* const* d_in, const int* in_sizes, int n_in,
                              void* d_out, int out_size, void* d_ws, size_t ws_size,
                              hipStream_t stream) {
  (void)in_sizes; (void)n_in; (void)out_size; (void)ws_size;
  const float* q  = (const float*)d_in[0];
  const float* k  = (const float*)d_in[1];
  const float* v  = (const float*)d_in[2];
  const float* Wq = (const float*)d_in[3];
  const float* bq = (const float*)d_in[4];
  const float* Wk = (const float*)d_in[5];
  const float* bk = (const float*)d_in[6];
  const float* Wv = (const float*)d_in[7];
  const float* bv = (const float*)d_in[8];
  const float* Wo = (const float*)d_in[9];
  const float* bo = (const float*)d_in[10];
  float* out = (float*)d_out;

  char* ws = (char*)d_ws;
  size_t off = 0;
  auto carve = [&](size_t bytes) { char* p = ws + off; off += (bytes + 255) & ~(size_t)255; return p; };
  u16* qb   = (u16*)carve((size_t)MM * DD * 2);
  u16* kb   = (u16*)carve((size_t)MM * DD * 2);
  u16* vb   = (u16*)carve((size_t)MM * DD * 2);
  u16* wqb  = (u16*)carve((size_t)DD * DD * 2);
  u16* wkb  = (u16*)carve((size_t)DD * DD * 2);
  u16* wvb  = (u16*)carve((size_t)DD * DD * 2);
  u16* wob  = (u16*)carve((size_t)DD * DD * 2);
  u16* Qro  = (u16*)carve((size_t)MM * DD * 2);
  u16* Kro  = (u16*)carve((size_t)MM * DD * 2);
  u16* Vtr  = (u16*)carve((size_t)MM * DD * 2);
  float2* tab = (float2*)carve((size_t)SS * 32 * 8);
  u16* Ob = qb;   // qb dead after gemm3_fused

  sincos_k<<<SS * 32 / 256, 256, 0, stream>>>(tab);
  conv_qkv<<<dim3(MM * DD / 1024, 3), 256, 0, stream>>>(q, k, v, qb, kb, vb);
  conv_w<<<dim3(DD * DD / 1024, 4), 256, 0, stream>>>(Wq, Wk, Wv, Wo, wqb, wkb, wvb, wob);
  gemm3_fused<<<dim3(DD / 128, MM / 64, 3), 256, 0, stream>>>(qb, kb, vb, wqb, wkb, wvb,
                                                              bq, bk, bv, Qro, Kro, Vtr, tab);
  attn_fwd<<<32 * BB * HH, 128, 0, stream>>>(Qro, Kro, Vtr, Ob);
  gemm_bt<<<dim3(DD / 128, MM / 64), 256, 0, stream>>>(Ob, wob, bo, out, MM, DD, DD);
}

// Round 6
// 263.982 us; speedup vs baseline: 1.8717x; 1.0193x over previous
//
#include <hip/hip_runtime.h>
#include <stdint.h>

// Problem constants
#define BB 2
#define SS 2048
#define DD 1024
#define HH 16
#define DH 64
#define MM 4096   // BB*SS

typedef __attribute__((ext_vector_type(8))) short short8;
typedef __attribute__((ext_vector_type(4))) float floatx4;
typedef __attribute__((ext_vector_type(16))) float floatx16;
typedef unsigned short u16;

#define MFMA16(a,b,c) __builtin_amdgcn_mfma_f32_16x16x32_bf16((a),(b),(c),0,0,0)
#define MFMA32(a,b,c) __builtin_amdgcn_mfma_f32_32x32x16_bf16((a),(b),(c),0,0,0)

__device__ __forceinline__ u16 f2bf(float f) {
  unsigned u = __float_as_uint(f);
  u += 0x7fffu + ((u >> 16) & 1u);
  return (u16)(u >> 16);
}

__device__ __forceinline__ unsigned cvtpk(float lo, float hi2) {
  unsigned r;
  asm("v_cvt_pk_bf16_f32 %0, %1, %2" : "=v"(r) : "v"(lo), "v"(hi2));
  return r;
}

__device__ __forceinline__ void gll16(const void* g, void* l) {
  __builtin_amdgcn_global_load_lds((const __attribute__((address_space(1))) void*)g,
                                   (__attribute__((address_space(3))) void*)l,
                                   16, 0, 0);
}

// ---------------- prep: sincos table + all fp32->bf16 conversions, one dispatch
// grid.x = 256 (sincos) + 3*4096 (q,k,v) + 4*1024 (Wq,Wk,Wv,Wo) = 16640 blocks
__global__ __launch_bounds__(256) void prep(
    const float* __restrict__ q, const float* __restrict__ k, const float* __restrict__ v,
    const float* __restrict__ Wq, const float* __restrict__ Wk,
    const float* __restrict__ Wv, const float* __restrict__ Wo,
    u16* __restrict__ qb, u16* __restrict__ kb, u16* __restrict__ vb,
    u16* __restrict__ wqb, u16* __restrict__ wkb, u16* __restrict__ wvb, u16* __restrict__ wob,
    float2* __restrict__ tab) {
  int bid = blockIdx.x;
  if (bid < 256) {                       // sincos: tab[s*32+j] = (sin(s*inv_j), cos(s*inv_j))
    const int t = bid * 256 + threadIdx.x;
    const int s = t >> 5, j = t & 31;
    const float inv = expf(-(float)j * (0.125f * 2.302585092994046f)); // 10^(-j/8)
    const float a = (float)s * inv;
    tab[t] = make_float2(sinf(a), cosf(a));
    return;
  }
  bid -= 256;
  const float* src;
  u16* dst;
  int x;
  if (bid < 12288) {                     // q,k,v: 3 x 4096 blocks
    const int z = bid >> 12;
    x = bid & 4095;
    src = z == 0 ? q : (z == 1 ? k : v);
    dst = z == 0 ? qb : (z == 1 ? kb : vb);
  } else {                               // weights: 4 x 1024 blocks
    bid -= 12288;
    const int z = bid >> 10;
    x = bid & 1023;
    src = z == 0 ? Wq : (z == 1 ? Wk : (z == 2 ? Wv : Wo));
    dst = z == 0 ? wqb : (z == 1 ? wkb : (z == 2 ? wvb : wob));
  }
  const int i = (x * 256 + threadIdx.x) * 4;
  const float4 xv = *(const float4*)(src + i);
  ushort4 p; p.x = f2bf(xv.x); p.y = f2bf(xv.y); p.z = f2bf(xv.z); p.w = f2bf(xv.w);
  *(ushort4*)(dst + i) = p;
}

// ---------------- GEMM core 128x128, BK=32, 4 waves 2x2 (m97 structure)
// acc[i<4][j<4]; row = m0 + (w>>1)*64 + i*16 + lq*4 + r; col = n0 + (w&1)*64 + j*16 + lr
__device__ __forceinline__ void gemm_core128(const u16* __restrict__ A, const u16* __restrict__ Bt,
                                             int K, u16* As, u16* Bs, floatx4 acc[4][4],
                                             int m0, int n0) {
  const int tid = threadIdx.x;
  const int w = tid >> 6, l = tid & 63;
  const int lr = l & 15, lq = l >> 4;
  const int wm = (w >> 1) * 64, wn = (w & 1) * 64;

#pragma unroll
  for (int i = 0; i < 4; ++i)
#pragma unroll
    for (int j = 0; j < 4; ++j) acc[i][j] = (floatx4){0.f, 0.f, 0.f, 0.f};

  const int srow = w * 32 + (l >> 2);
  const int scol = (l & 3) * 8;
  const u16* ag = A + (size_t)(m0 + srow) * K + scol;
  const u16* bg = Bt + (size_t)(n0 + srow) * K + scol;
  u16* as0 = &As[w * 1024];
  u16* bs0 = &Bs[w * 1024];

  for (int k0 = 0; k0 < K; k0 += 32) {
    gll16(ag + k0, as0);
    gll16(ag + (size_t)16 * K + k0, as0 + 512);
    gll16(bg + k0, bs0);
    gll16(bg + (size_t)16 * K + k0, bs0 + 512);
    __syncthreads();
    short8 af[4], bfv[4];
#pragma unroll
    for (int i = 0; i < 4; ++i) af[i] = *(const short8*)&As[(wm + i * 16 + lr) * 32 + lq * 8];
#pragma unroll
    for (int j = 0; j < 4; ++j) bfv[j] = *(const short8*)&Bs[(wn + j * 16 + lr) * 32 + lq * 8];
    __builtin_amdgcn_s_setprio(1);
#pragma unroll
    for (int i = 0; i < 4; ++i)
#pragma unroll
      for (int j = 0; j < 4; ++j) acc[i][j] = MFMA16(af[i], bfv[j], acc[i][j]);
    __builtin_amdgcn_s_setprio(0);
    __syncthreads();
  }
}

// ---------------- GEMM core 64x128, BK=32 (for the 256-tile out-projection: 512 blocks)
__device__ __forceinline__ void gemm_core64(const u16* __restrict__ A, const u16* __restrict__ Bt,
                                            int K, u16* As, u16* Bs, floatx4 acc[2][4],
                                            int m0, int n0) {
  const int tid = threadIdx.x;
  const int w = tid >> 6, l = tid & 63;
  const int lr = l & 15, lq = l >> 4;
  const int wm = (w >> 1) * 32, wn = (w & 1) * 64;

#pragma unroll
  for (int i = 0; i < 2; ++i)
#pragma unroll
    for (int j = 0; j < 4; ++j) acc[i][j] = (floatx4){0.f, 0.f, 0.f, 0.f};

  const int arow = w * 16 + (l >> 2);
  const int brow = w * 32 + (l >> 2);
  const int scol = (l & 3) * 8;
  const u16* ag = A + (size_t)(m0 + arow) * K + scol;
  const u16* bg = Bt + (size_t)(n0 + brow) * K + scol;
  u16* as0 = &As[w * 512];
  u16* bs0 = &Bs[w * 1024];

  for (int k0 = 0; k0 < K; k0 += 32) {
    gll16(ag + k0, as0);
    gll16(bg + k0, bs0);
    gll16(bg + (size_t)16 * K + k0, bs0 + 512);
    __syncthreads();
    short8 af[2], bfv[4];
#pragma unroll
    for (int i = 0; i < 2; ++i) af[i] = *(const short8*)&As[(wm + i * 16 + lr) * 32 + lq * 8];
#pragma unroll
    for (int j = 0; j < 4; ++j) bfv[j] = *(const short8*)&Bs[(wn + j * 16 + lr) * 32 + lq * 8];
    __builtin_amdgcn_s_setprio(1);
#pragma unroll
    for (int i = 0; i < 2; ++i)
#pragma unroll
      for (int j = 0; j < 4; ++j) acc[i][j] = MFMA16(af[i], bfv[j], acc[i][j]);
    __builtin_amdgcn_s_setprio(0);
    __syncthreads();
  }
}

// fused q/k/v projections (128x128 tile) + RoPE/pack (z=0 Q, z=1 K) or V-transpose (z=2)
__global__ __launch_bounds__(256) void gemm3_fused(
    const u16* __restrict__ A0, const u16* __restrict__ A1, const u16* __restrict__ A2,
    const u16* __restrict__ B0, const u16* __restrict__ B1, const u16* __restrict__ B2,
    const float* __restrict__ c0, const float* __restrict__ c1, const float* __restrict__ c2,
    u16* __restrict__ Qro, u16* __restrict__ Kro, u16* __restrict__ Vtr,
    const float2* __restrict__ tab) {
  __shared__ alignas(16) u16 As[128 * 32];
  __shared__ alignas(16) u16 Bs[128 * 32];
  const int z = blockIdx.z;
  const u16* A = z == 0 ? A0 : (z == 1 ? A1 : A2);
  const u16* Bt = z == 0 ? B0 : (z == 1 ? B1 : B2);
  const float* bias = z == 0 ? c0 : (z == 1 ? c1 : c2);
  const int m0 = blockIdx.y * 128, n0 = blockIdx.x * 128;

  floatx4 acc[4][4];
  gemm_core128(A, Bt, DD, As, Bs, acc, m0, n0);

  const int tid = threadIdx.x;
  const int w = tid >> 6, l = tid & 63;
  const int lr = l & 15, lq = l >> 4;
  const int wm = (w >> 1) * 64, wn = (w & 1) * 64;

  if (z == 2) {
    // V^T: Vt[((b*16+h)*64 + e)*SS + s], bias added, bf16
#pragma unroll
    for (int i = 0; i < 4; ++i) {
      const int row = m0 + wm + i * 16 + lq * 4;   // 4 consecutive s from here
      const int b = row >> 11, s = row & (SS - 1);
#pragma unroll
      for (int j = 0; j < 4; ++j) {
        const int col = n0 + wn + j * 16 + lr;
        const int h = col >> 6, e = col & 63;
        const float bv = bias[col];
        ushort4 pk;
        pk.x = f2bf(acc[i][j][0] + bv);
        pk.y = f2bf(acc[i][j][1] + bv);
        pk.z = f2bf(acc[i][j][2] + bv);
        pk.w = f2bf(acc[i][j][3] + bv);
        *(ushort4*)(Vtr + ((size_t)(b * HH + h) * DH + e) * SS + s) = pk;
      }
    }
  } else {
    u16* dst = z ? Kro : Qro;
#pragma unroll
    for (int i = 0; i < 4; ++i) {
#pragma unroll
      for (int j = 0; j < 4; ++j) {
        const int col = n0 + wn + j * 16 + lr;
        const int h = col >> 6, e = col & 63;
        const float bv = bias[col];
#pragma unroll
        for (int r = 0; r < 4; ++r) {
          const int row = m0 + wm + i * 16 + lq * 4 + r;
          const int b = row >> 11, s = row & (SS - 1);
          const float v = acc[i][j][r] + bv;
          const float p = __shfl_xor(v, 1);     // even/odd partner (col^1 <-> lane^1)
          const float2 sc = tab[s * 32 + (e >> 1)];
          const float ov = ((e & 1) == 0) ? (v * sc.x - p * sc.y)     //  x1*sin - x2*cos
                                          : (-p * sc.y - v * sc.x);   // -x1*cos - x2*sin
          dst[((size_t)(b * HH + h) * SS + s) * DH + e] = f2bf(ov);
        }
      }
    }
  }
}

// out-projection: C fp32 = A(bf16) * Bt^T + bias  (64x128 tile -> 512 blocks, 2/CU)
__global__ __launch_bounds__(256) void gemm_bt(const u16* __restrict__ A, const u16* __restrict__ Bt,
                                               const float* __restrict__ bias, float* __restrict__ C,
                                               int M, int N, int K) {
  __shared__ alignas(16) u16 As[64 * 32];
  __shared__ alignas(16) u16 Bs[128 * 32];
  const int m0 = blockIdx.y * 64, n0 = blockIdx.x * 128;
  floatx4 acc[2][4];
  gemm_core64(A, Bt, K, As, Bs, acc, m0, n0);

  const int tid = threadIdx.x;
  const int w = tid >> 6, l = tid & 63;
  const int lr = l & 15, lq = l >> 4;
  const int wm = (w >> 1) * 32, wn = (w & 1) * 64;
#pragma unroll
  for (int i = 0; i < 2; ++i) {
    const int row = m0 + wm + i * 16 + lq * 4;
#pragma unroll
    for (int j = 0; j < 4; ++j) {
      const int col = n0 + wn + j * 16 + lr;
      const float bv = bias[col];
      float* cp = C + (size_t)row * N + col;
#pragma unroll
      for (int r = 0; r < 4; ++r) cp[(size_t)r * N] = acc[i][j][r] + bv;
    }
  }
}

// ---------------- causal flash attention, swapped-operand 32x32 (R3 structure: 4 waves x 32 q)
// Q,K bf16 [bh][s][64]; V bf16 [bh][64][s]; O bf16 [b][s][h*64+e]
// S^T = mfma(K, Q): col=q (lane&31) -> softmax lane-local + 1 shfl(32); in-register P.
__global__ __launch_bounds__(256) void attn_fwd(const u16* __restrict__ Qr, const u16* __restrict__ Kr,
                                                const u16* __restrict__ Vt, u16* __restrict__ O) {
  __shared__ alignas(16) u16 Ks[2][64 * 64];
  __shared__ alignas(16) u16 Vs[2][64 * 64];
  const int bid = blockIdx.x;
  const int qt = 15 - (bid >> 5);              // heavy q-tiles first
  const int bh = bid & 31;
  const int w = threadIdx.x >> 6, l = threadIdx.x & 63;
  const int ql = l & 31, hi = l >> 5;
  const int qw0 = qt * 128 + w * 32;           // this wave's 32 q rows
  const u16* Qh = Qr + (size_t)bh * SS * DH;
  const u16* Kh = Kr + (size_t)bh * SS * DH;
  const u16* Vh = Vt + (size_t)bh * DH * SS;

  short8 qf[4];
#pragma unroll
  for (int i = 0; i < 4; ++i)
    qf[i] = *(const short8*)(Qh + (size_t)(qw0 + ql) * DH + i * 16 + hi * 8);

  floatx16 oacc[2];
#pragma unroll
  for (int dt = 0; dt < 2; ++dt)
#pragma unroll
    for (int r = 0; r < 16; ++r) oacc[dt][r] = 0.f;
  float mrun = -1e30f, lrun = 0.f;

  // staging: wave w covers rows [16w,16w+16) of each 64x(64 u16) tile, 2 gll16 per array
  const int srow = w * 16 + (l >> 3);
  const int sgofs = ((((l & 7) * 16) ^ (((l >> 3) & 7) << 4)) >> 1);   // swizzled src col (u16)
  const int swzb = (ql & 7) << 4;              // read-side swizzle (byte)

#define STAGE(buf, kv0)                                                                  \
  do {                                                                                   \
    gll16(Kh + (size_t)((kv0) + srow) * DH + sgofs,       &Ks[buf][(w * 16) * 64]);      \
    gll16(Kh + (size_t)((kv0) + srow + 8) * DH + sgofs,   &Ks[buf][(w * 16 + 8) * 64]);  \
    gll16(Vh + (size_t)srow * SS + (kv0) + sgofs,         &Vs[buf][(w * 16) * 64]);      \
    gll16(Vh + (size_t)(srow + 8) * SS + (kv0) + sgofs,   &Vs[buf][(w * 16 + 8) * 64]);  \
  } while (0)

  const int T = 2 * qt + 2;
  STAGE(0, 0);
  __syncthreads();

  for (int t = 0; t < T; ++t) {
    const int cur = t & 1;
    if (t < T - 1) STAGE(cur ^ 1, (t + 1) * 64);
    const int kv0 = t * 64;

    if (kv0 <= qw0 + 31) {                     // wave-level causal skip (barrier stays uniform)
      // ---- S^T = K · Q^T  (rows=kv, cols=q)
      floatx16 st[2];
#pragma unroll
      for (int tt = 0; tt < 2; ++tt)
#pragma unroll
        for (int r = 0; r < 16; ++r) st[tt][r] = 0.f;
      __builtin_amdgcn_s_setprio(1);
#pragma unroll
      for (int tt = 0; tt < 2; ++tt)
#pragma unroll
        for (int i = 0; i < 4; ++i) {
          const u16* kp = &Ks[cur][(tt * 32 + ql) * 64 + (((32 * i + 16 * hi) ^ swzb) >> 1)];
          st[tt] = MFMA32(*(const short8*)kp, qf[i], st[tt]);
        }
      __builtin_amdgcn_s_setprio(0);

      if (kv0 + 63 > qw0) {                    // diagonal: mask kv > q
#pragma unroll
        for (int tt = 0; tt < 2; ++tt)
#pragma unroll
          for (int r = 0; r < 16; ++r) {
            const int kv = kv0 + tt * 32 + (r & 3) + 8 * (r >> 2) + 4 * hi;
            if (kv > qw0 + ql) st[tt][r] = -1e30f;
          }
      }

      // ---- online softmax: lane-local max over 32 kv + one shfl(32); rescale every tile
      floatx16 mx;
#pragma unroll
      for (int r = 0; r < 16; ++r) mx[r] = fmaxf(st[0][r], st[1][r]);
      float m8[8];
#pragma unroll
      for (int r = 0; r < 8; ++r) m8[r] = fmaxf(mx[r], mx[r + 8]);
      float m4a = fmaxf(m8[0], m8[4]), m4b = fmaxf(m8[1], m8[5]);
      float m4c = fmaxf(m8[2], m8[6]), m4d = fmaxf(m8[3], m8[7]);
      float tmax = fmaxf(fmaxf(m4a, m4b), fmaxf(m4c, m4d));
      tmax = fmaxf(tmax, __shfl_xor(tmax, 32));

      const float mn = fmaxf(mrun, tmax);
      const float sc = __expf(mrun - mn);
      mrun = mn;
      float ps = 0.f;
#pragma unroll
      for (int tt = 0; tt < 2; ++tt)
#pragma unroll
        for (int r = 0; r < 16; ++r) {
          const float p = __expf(st[tt][r] - mn);
          st[tt][r] = p;
          ps += p;
        }
      ps += __shfl_xor(ps, 32);
      lrun = lrun * sc + ps;
#pragma unroll
      for (int dt = 0; dt < 2; ++dt)
#pragma unroll
        for (int r = 0; r < 16; ++r) oacc[dt][r] *= sc;

      // ---- pack P^T into PV B-fragments (in-register, lane^32 exchange)
      short8 pfrag[4];
#pragma unroll
      for (int c = 0; c < 4; ++c) {
        const int tt = c >> 1;
        const int A0r = 2 * (c & 1), A1r = A0r + 1;
        const unsigned P00 = cvtpk(st[tt][4 * A0r + 0], st[tt][4 * A0r + 1]);
        const unsigned P01 = cvtpk(st[tt][4 * A0r + 2], st[tt][4 * A0r + 3]);
        const unsigned P10 = cvtpk(st[tt][4 * A1r + 0], st[tt][4 * A1r + 1]);
        const unsigned P11 = cvtpk(st[tt][4 * A1r + 2], st[tt][4 * A1r + 3]);
        const unsigned S0 = hi ? P00 : P10;
        const unsigned S1 = hi ? P01 : P11;
        const unsigned R0 = (unsigned)__shfl_xor((int)S0, 32);
        const unsigned R1 = (unsigned)__shfl_xor((int)S1, 32);
        union { unsigned u[4]; short8 s; } fd;
        fd.u[0] = hi ? R0 : P00;
        fd.u[1] = hi ? R1 : P01;
        fd.u[2] = hi ? P10 : R0;
        fd.u[3] = hi ? P11 : R1;
        pfrag[c] = fd.s;
      }

      // ---- O^T += V^T · P^T  (rows=d, cols=q)
      __builtin_amdgcn_s_setprio(1);
#pragma unroll
      for (int dt = 0; dt < 2; ++dt)
#pragma unroll
        for (int c = 0; c < 4; ++c) {
          const u16* vp = &Vs[cur][(dt * 32 + ql) * 64 + (((32 * c + 16 * hi) ^ swzb) >> 1)];
          oacc[dt] = MFMA32(*(const short8*)vp, pfrag[c], oacc[dt]);
        }
      __builtin_amdgcn_s_setprio(0);
    }
    __syncthreads();   // drains this iter's STAGE (implicit vmcnt); next iter reads cur^1
  }
#undef STAGE

  // ---- epilogue: lane owns q = qw0+ql; d = dt*32 + 8g + 4hi + 0..3
  const float inv = 1.0f / lrun;
  const int b = bh >> 4, h = bh & 15;
  u16* orow = O + ((size_t)(b * SS + qw0 + ql)) * DD + h * DH;
#pragma unroll
  for (int dt = 0; dt < 2; ++dt)
#pragma unroll
    for (int g = 0; g < 4; ++g) {
      ushort4 pk;
      pk.x = f2bf(oacc[dt][4 * g + 0] * inv);
      pk.y = f2bf(oacc[dt][4 * g + 1] * inv);
      pk.z = f2bf(oacc[dt][4 * g + 2] * inv);
      pk.w = f2bf(oacc[dt][4 * g + 3] * inv);
      *(ushort4*)(orow + dt * 32 + 8 * g + 4 * hi) = pk;
    }
}

extern "C" void kernel_launch(void* const* d_in, const int* in_sizes, int n_in,
                              void* d_out, int out_size, void* d_ws, size_t ws_size,
                              hipStream_t stream) {
  (void)in_sizes; (void)n_in; (void)out_size; (void)ws_size;
  const float* q  = (const float*)d_in[0];
  const float* k  = (const float*)d_in[1];
  const float* v  = (const float*)d_in[2];
  const float* Wq = (const float*)d_in[3];
  const float* bq = (const float*)d_in[4];
  const float* Wk = (const float*)d_in[5];
  const float* bk = (const float*)d_in[6];
  const float* Wv = (const float*)d_in[7];
  const float* bv = (const float*)d_in[8];
  const float* Wo = (const float*)d_in[9];
  const float* bo = (const float*)d_in[10];
  float* out = (float*)d_out;

  char* ws = (char*)d_ws;
  size_t off = 0;
  auto carve = [&](size_t bytes) { char* p = ws + off; off += (bytes + 255) & ~(size_t)255; return p; };
  u16* qb   = (u16*)carve((size_t)MM * DD * 2);
  u16* kb   = (u16*)carve((size_t)MM * DD * 2);
  u16* vb   = (u16*)carve((size_t)MM * DD * 2);
  u16* wqb  = (u16*)carve((size_t)DD * DD * 2);
  u16* wkb  = (u16*)carve((size_t)DD * DD * 2);
  u16* wvb  = (u16*)carve((size_t)DD * DD * 2);
  u16* wob  = (u16*)carve((size_t)DD * DD * 2);
  u16* Qro  = (u16*)carve((size_t)MM * DD * 2);
  u16* Kro  = (u16*)carve((size_t)MM * DD * 2);
  u16* Vtr  = (u16*)carve((size_t)MM * DD * 2);
  float2* tab = (float2*)carve((size_t)SS * 32 * 8);
  u16* Ob = qb;   // qb dead after gemm3_fused

  prep<<<256 + 3 * 4096 + 4 * 1024, 256, 0, stream>>>(q, k, v, Wq, Wk, Wv, Wo,
                                                      qb, kb, vb, wqb, wkb, wvb, wob, tab);
  gemm3_fused<<<dim3(DD / 128, MM / 128, 3), 256, 0, stream>>>(qb, kb, vb, wqb, wkb, wvb,
                                                               bq, bk, bv, Qro, Kro, Vtr, tab);
  attn_fwd<<<16 * BB * HH, 256, 0, stream>>>(Qro, Kro, Vtr, Ob);
  gemm_bt<<<dim3(DD / 128, MM / 64), 256, 0, stream>>>(Ob, wob, bo, out, MM, DD, DD);
}